// Round 1
// baseline (268.364 us; speedup 1.0000x reference)
//
#include <hip/hip_runtime.h>
#include <math.h>

#define NTAP 16
#define TS   32
#define IMG  512
#define NIMG 24            // 8*3 depthwise-independent images
#define XPH  62            // TS + 30 rows of padded input tile
#define XPW  64            // padded width (cols 62,63 zero-filled)
#define TW   48            // first hconv output width (47 used + 1 garbage col)
#define THGT 62
#define RW   48
#define RH   47
#define UW   32
#define UH   47

// ---------------- init per-image min/max slots ----------------
__global__ void stego_init(int* __restrict__ mn, int* __restrict__ mx) {
    int t = threadIdx.x;
    if (t < NIMG) {
        mn[t] = __float_as_int(1e38f);  // rho >= 0, int ordering valid for nonneg floats
        mx[t] = 0;                      // == __float_as_int(0.0f)
    }
}

// ---------------- stage 1: rho + per-image min/max ----------------
__global__ __launch_bounds__(256) void stego_stage1(
    const float* __restrict__ x, const float* __restrict__ hpdf,
    float* __restrict__ rho_out, int* __restrict__ mnbuf, int* __restrict__ mxbuf)
{
    __shared__ float sXP[XPH * XPW];   // 3968 floats
    __shared__ float sT [THGT * TW];   // 2976 floats (reused as U: 47x32)
    __shared__ float sR [RH * RW];     // 2256 floats
    __shared__ float cH[NTAP], cL[NTAP], cHA[NTAP], cHAR[NTAP];
    __shared__ float red[16];

    const int tid = threadIdx.x;
    const int Oj = blockIdx.x * TS;
    const int Oi = blockIdx.y * TS;
    const int img = blockIdx.z;
    const float* ximg = x + (size_t)img * IMG * IMG;

    if (tid < NTAP) {
        float h  = hpdf[tid];
        float hr = hpdf[15 - tid];
        cH[tid]   = h;
        cHA[tid]  = fabsf(h);
        cL[tid]   = (tid & 1) ? -hr : hr;   // lpdf[k] = (-1)^k * hpdf[15-k]
        cHAR[tid] = fabsf(hr);
    }

    // load reflect-padded 62x62 tile (width padded to 64 with zeros)
    for (int e = tid; e < XPH * XPW; e += 256) {
        int i = e >> 6;
        int j = e & 63;
        float v = 0.f;
        if (j < 62) {
            int gi = Oi + i - 15; gi = (gi < 0) ? -gi : ((gi >= IMG) ? 2 * IMG - 2 - gi : gi);
            int gj = Oj + j - 15; gj = (gj < 0) ? -gj : ((gj >= IMG) ? 2 * IMG - 2 - gj : gj);
            v = ximg[gi * IMG + gj];
        }
        sXP[e] = v;
    }
    __syncthreads();

    const int J  = tid & 31;
    const int I0 = (tid >> 5) * 4;
    float rho[4] = {0.f, 0.f, 0.f, 0.f};

    for (int f = 0; f < 3; ++f) {
        // filters: LH = outer(lpdf,hpdf), HL = outer(hpdf,lpdf), HH = outer(hpdf,hpdf)
        // f[u,v] = a[u]*b[v]; second conv uses |f[::-1,::-1]| = a2[u]*b2[v]
        const float* a  = (f == 0) ? cL   : cH;
        const float* b  = (f == 1) ? cL   : cH;
        const float* a2 = (f == 0) ? cHA  : cHAR;   // |a[15-u]|
        const float* b2 = (f == 1) ? cHA  : cHAR;   // |b[15-v]|

        // ---- stage A: horizontal conv, T[i][j] = sum_v b[v]*XP[i][j+v] ----
        {
            float c[NTAP];
            #pragma unroll
            for (int k = 0; k < NTAP; ++k) c[k] = b[k];
            for (int e = tid; e < THGT * 12; e += 256) {   // 744 groups of 4 outputs
                int gi = e / 12;
                int j0 = (e - gi * 12) * 4;
                const float* base = &sXP[gi * XPW + j0];
                float w[19];
                #pragma unroll
                for (int k = 0; k < 19; ++k) w[k] = base[k];   // j0<=44 -> max col 62 (zero pad) OK
                #pragma unroll
                for (int t = 0; t < 4; ++t) {
                    float s = 0.f;
                    #pragma unroll
                    for (int v = 0; v < NTAP; ++v) s = fmaf(c[v], w[t + v], s);
                    sT[gi * TW + j0 + t] = s;
                }
            }
        }
        __syncthreads();

        // ---- stage B: vertical conv + abs, R[i][j] = |sum_u a[u]*T[i+u][j]| ----
        {
            float c[NTAP];
            #pragma unroll
            for (int k = 0; k < NTAP; ++k) c[k] = a[k];
            for (int e = tid; e < 12 * RW; e += 256) {      // 576 groups
                int gi = e / RW;
                int j  = e - gi * RW;
                int i0 = gi * 4;
                float w[19];
                #pragma unroll
                for (int k = 0; k < 18; ++k) w[k] = sT[(i0 + k) * TW + j];  // i0<=44 -> row<=61 OK
                w[18] = (i0 + 18 < THGT) ? sT[(i0 + 18) * TW + j] : 0.f;
                #pragma unroll
                for (int t = 0; t < 4; ++t) {
                    float s = 0.f;
                    #pragma unroll
                    for (int v = 0; v < NTAP; ++v) s = fmaf(c[v], w[t + v], s);
                    if (i0 + t < RH) sR[(i0 + t) * RW + j] = fabsf(s);
                }
            }
        }
        __syncthreads();

        // ---- stage C: horizontal conv, U[i][j] = sum_v b2[v]*|R|[i][j+v] (U aliases sT) ----
        {
            float c[NTAP];
            #pragma unroll
            for (int k = 0; k < NTAP; ++k) c[k] = b2[k];
            for (int e = tid; e < UH * 8; e += 256) {       // 376 groups
                int i  = e >> 3;
                int j0 = (e & 7) * 4;
                const float* base = &sR[i * RW + j0];
                float w[19];
                #pragma unroll
                for (int k = 0; k < 19; ++k) w[k] = base[k];   // j0<=28 -> max col 46 < 48 OK
                #pragma unroll
                for (int t = 0; t < 4; ++t) {
                    float s = 0.f;
                    #pragma unroll
                    for (int v = 0; v < NTAP; ++v) s = fmaf(c[v], w[t + v], s);
                    sT[i * UW + j0 + t] = s;
                }
            }
        }
        __syncthreads();

        // ---- stage D: vertical conv, xi[I][J] = sum_u a2[u]*U[I+u][J]; rho += 1/xi ----
        {
            float c[NTAP];
            #pragma unroll
            for (int k = 0; k < NTAP; ++k) c[k] = a2[k];
            float w[19];
            #pragma unroll
            for (int k = 0; k < 19; ++k) w[k] = sT[(I0 + k) * UW + J];  // I0<=28 -> row<=46 OK
            #pragma unroll
            for (int t = 0; t < 4; ++t) {
                float s = 0.f;
                #pragma unroll
                for (int v = 0; v < NTAP; ++v) s = fmaf(c[v], w[t + v], s);
                rho[t] += 1.0f / s;
            }
        }
        __syncthreads();   // before next filter overwrites sT
    }

    // finalize: clamp/NaN, store rho (unrolled position), local min/max
    float lmin = 1e38f, lmax = 0.f;
    const size_t rbase = (size_t)img * IMG * IMG;
    #pragma unroll
    for (int t = 0; t < 4; ++t) {
        float r = rho[t];
        r = isnan(r) ? 1e10f : fminf(r, 1e10f);
        rho_out[rbase + (size_t)(Oi + I0 + t) * IMG + (Oj + J)] = r;
        lmin = fminf(lmin, r);
        lmax = fmaxf(lmax, r);
    }

    // wave64 butterfly + cross-wave via LDS
    #pragma unroll
    for (int off = 32; off >= 1; off >>= 1) {
        lmin = fminf(lmin, __shfl_xor(lmin, off));
        lmax = fmaxf(lmax, __shfl_xor(lmax, off));
    }
    int wid = tid >> 6;
    if ((tid & 63) == 0) { red[wid] = lmin; red[8 + wid] = lmax; }
    __syncthreads();
    if (tid == 0) {
        float m0 = red[0], m1 = red[8];
        #pragma unroll
        for (int k = 1; k < 4; ++k) { m0 = fminf(m0, red[k]); m1 = fmaxf(m1, red[8 + k]); }
        atomicMin(&mnbuf[img], __float_as_int(m0));
        atomicMax(&mxbuf[img], __float_as_int(m1));
    }
}

// ---------------- stage 2: normalize + sigmoid + multiply ----------------
__global__ __launch_bounds__(256) void stego_stage2(
    const float* __restrict__ x, const float* __restrict__ rho,
    const int* __restrict__ mnbuf, const int* __restrict__ mxbuf,
    float* __restrict__ out)
{
    int idx = blockIdx.x * 256 + threadIdx.x;
    int img = idx >> 18;                 // / (512*512)
    int pos = idx & (IMG * IMG - 1);
    int i = pos >> 9, j = pos & 511;
    float mn = __int_as_float(mnbuf[img]);
    float mx = __int_as_float(mxbuf[img]);
    // roll by +1 on both spatial dims == read rho at (i-1, j-1) with wrap
    float r = rho[((size_t)img << 18) + (size_t)(((i - 1) & 511) << 9) + ((j - 1) & 511)];
    float rn = (r - mn) / (mx - mn + 1e-8f);
    float score = 1.0f / (1.0f + expf(rn - 1.0f));   // sigmoid(1 - rn)
    out[idx] = x[idx] * score;
}

extern "C" void kernel_launch(void* const* d_in, const int* in_sizes, int n_in,
                              void* d_out, int out_size, void* d_ws, size_t ws_size,
                              hipStream_t stream) {
    const float* x    = (const float*)d_in[0];
    const float* hpdf = (const float*)d_in[1];
    float* out = (float*)d_out;

    float* rho  = (float*)d_ws;                                     // 24*512*512 floats
    int* mnbuf  = (int*)((char*)d_ws + (size_t)NIMG * IMG * IMG * sizeof(float));
    int* mxbuf  = mnbuf + NIMG;

    hipLaunchKernelGGL(stego_init, dim3(1), dim3(64), 0, stream, mnbuf, mxbuf);
    hipLaunchKernelGGL(stego_stage1, dim3(IMG / TS, IMG / TS, NIMG), dim3(256), 0, stream,
                       x, hpdf, rho, mnbuf, mxbuf);
    const int total = NIMG * IMG * IMG;
    hipLaunchKernelGGL(stego_stage2, dim3(total / 256), dim3(256), 0, stream,
                       x, rho, mnbuf, mxbuf, out);
}

// Round 2
// 207.077 us; speedup vs baseline: 1.2960x; 1.2960x over previous
//
#include <hip/hip_runtime.h>
#include <math.h>

#define IMG  512
#define NIMG 24            // 8*3 depthwise-independent images
#define TS   32
#define SX   63            // X tile row stride (odd -> conflict-free column access)
#define ST   65            // T/R/U row stride (odd)
#define NBUF (64 * ST)     // 4160 floats per buffer

// ---------------- init per-image min/max slots ----------------
__global__ void stego_init(int* __restrict__ mn, int* __restrict__ mx) {
    int t = threadIdx.x;
    if (t < NIMG) {
        mn[t] = __float_as_int(1e38f);  // rho >= 0, int ordering valid for nonneg floats
        mx[t] = 0;
    }
}

// coefficient modes (h = hpdf, lpdf[v] = (-1)^v h[15-v]):
// 0: h[v] (cH)   1: lpdf[v] (cL)   2: |h[v]| (cHA)   3: |h[15-v]| (cHAR)
template<int MODE>
__device__ __forceinline__ float coef(const float* __restrict__ h, int v) {
    if (MODE == 0) return h[v];
    if (MODE == 1) return (v & 1) ? -h[15 - v] : h[15 - v];
    if (MODE == 2) return fabsf(h[v]);
    return fabsf(h[15 - v]);
}

// horizontal conv: thread = row (tid&63), wave = segment of LEN output columns.
// Window read is contiguous; banks across lanes = lane*SRCS mod 32 (odd stride -> conflict-free).
template<int MODE, int LEN, int SRCS, int DSTS>
__device__ __forceinline__ void hconv(const float* __restrict__ src, float* __restrict__ dst,
                                      const float* __restrict__ h, int tid) {
    const int line = tid & 63, s = tid >> 6;
    const float* p = src + line * SRCS + s * LEN;
    float w[LEN + 15];
    #pragma unroll
    for (int k = 0; k < LEN + 15; ++k) w[k] = p[k];
    float* q = dst + line * DSTS + s * LEN;
    #pragma unroll
    for (int o = 0; o < LEN; ++o) {
        float acc = 0.f;
        #pragma unroll
        for (int v = 0; v < 16; ++v) acc = fmaf(coef<MODE>(h, v), w[o + v], acc);
        q[o] = acc;
    }
}

// vertical conv: thread = column (tid&63), wave = segment of LEN output rows.
// Column reads are stride-1 across lanes -> conflict-free.
template<int MODE, int LEN, int SRCS, int DSTS, bool ABS>
__device__ __forceinline__ void vconv(const float* __restrict__ src, float* __restrict__ dst,
                                      const float* __restrict__ h, int tid) {
    const int col = tid & 63, s = tid >> 6;
    const int i0 = s * LEN;
    const float* p = src + i0 * SRCS + col;
    float w[LEN + 15];
    #pragma unroll
    for (int k = 0; k < LEN + 15; ++k) w[k] = p[k * SRCS];
    float* q = dst + i0 * DSTS + col;
    #pragma unroll
    for (int o = 0; o < LEN; ++o) {
        float acc = 0.f;
        #pragma unroll
        for (int v = 0; v < 16; ++v) acc = fmaf(coef<MODE>(h, v), w[o + v], acc);
        q[o * DSTS] = ABS ? fabsf(acc) : acc;
    }
}

// final vertical conv: 32 real columns x 8 segments of 4 rows; accumulate rho in regs.
template<int MODE>
__device__ __forceinline__ void vconv_rho(const float* __restrict__ U,
                                          const float* __restrict__ h, int tid, float rho[4]) {
    const int col = tid & 31, s = tid >> 5, i0 = s * 4;
    const float* p = U + i0 * ST + col;
    float w[19];
    #pragma unroll
    for (int k = 0; k < 19; ++k) w[k] = p[k * ST];
    #pragma unroll
    for (int o = 0; o < 4; ++o) {
        float acc = 0.f;
        #pragma unroll
        for (int v = 0; v < 16; ++v) acc = fmaf(coef<MODE>(h, v), w[o + v], acc);
        rho[o] += 1.0f / acc;
    }
}

// ---------------- stage 1: rho + per-image min/max ----------------
__global__ __launch_bounds__(256) void stego_stage1(
    const float* __restrict__ x, const float* __restrict__ hpdf,
    float* __restrict__ rho_out, int* __restrict__ mnbuf, int* __restrict__ mxbuf)
{
    __shared__ float BufA[NBUF];   // X (stride 63), then R (stride 65)
    __shared__ float Buf1[NBUF];   // T_L, then U
    __shared__ float Buf2[NBUF];   // T_H (kept across LH and HH)
    __shared__ float red[16];

    const int tid = threadIdx.x;
    const int Oj = blockIdx.x * TS;
    const int Oi = blockIdx.y * TS;
    const int img = blockIdx.z;
    const float* ximg = x + (size_t)img * IMG * IMG;

    // load reflect-padded 62x62 tile into BufA (64x63, zeros in slack rows/cols)
    for (int e = tid; e < 64 * SX; e += 256) {
        int i = e / SX, j = e - i * SX;
        float v = 0.f;
        if (i < 62 && j < 62) {
            int gi = Oi + i - 15; gi = (gi < 0) ? -gi : ((gi >= IMG) ? 2 * IMG - 2 - gi : gi);
            int gj = Oj + j - 15; gj = (gj < 0) ? -gj : ((gj >= IMG) ? 2 * IMG - 2 - gj : gj);
            v = ximg[gi * IMG + gj];
        }
        BufA[e] = v;
    }
    __syncthreads();

    // stage A (shared): T_L = hconv_L(X), T_H = hconv_H(X)  [H feeds both LH and HH]
    hconv<1, 12, SX, ST>(BufA, Buf1, hpdf, tid);   // T_L
    hconv<0, 12, SX, ST>(BufA, Buf2, hpdf, tid);   // T_H
    __syncthreads();

    float rho[4] = {0.f, 0.f, 0.f, 0.f};

    // ---- HL: a=H, b=L (T_L), b2=|h| (mode2), a2=|h rev| (mode3) ----
    vconv<0, 12, ST, ST, true>(Buf1, BufA, hpdf, tid);   // R = |vconv_H(T_L)|
    __syncthreads();
    hconv<2, 8, ST, ST>(BufA, Buf1, hpdf, tid);          // U
    __syncthreads();
    vconv_rho<3>(Buf1, hpdf, tid, rho);
    __syncthreads();

    // ---- LH: a=L (T_H), b2=|h rev| (mode3), a2=|h| (mode2) ----
    vconv<1, 12, ST, ST, true>(Buf2, BufA, hpdf, tid);
    __syncthreads();
    hconv<3, 8, ST, ST>(BufA, Buf1, hpdf, tid);
    __syncthreads();
    vconv_rho<2>(Buf1, hpdf, tid, rho);
    __syncthreads();

    // ---- HH: a=H (T_H), b2=|h rev| (mode3), a2=|h rev| (mode3) ----
    vconv<0, 12, ST, ST, true>(Buf2, BufA, hpdf, tid);
    __syncthreads();
    hconv<3, 8, ST, ST>(BufA, Buf1, hpdf, tid);
    __syncthreads();
    vconv_rho<3>(Buf1, hpdf, tid, rho);

    // finalize: clamp/NaN, store rho, per-image min/max (I0=(tid>>5)*4, J=tid&31)
    const int J  = tid & 31;
    const int I0 = (tid >> 5) * 4;
    float lmin = 1e38f, lmax = 0.f;
    const size_t rbase = (size_t)img * IMG * IMG;
    #pragma unroll
    for (int t = 0; t < 4; ++t) {
        float r = rho[t];
        r = isnan(r) ? 1e10f : fminf(r, 1e10f);
        rho_out[rbase + (size_t)(Oi + I0 + t) * IMG + (Oj + J)] = r;
        lmin = fminf(lmin, r);
        lmax = fmaxf(lmax, r);
    }

    #pragma unroll
    for (int off = 32; off >= 1; off >>= 1) {
        lmin = fminf(lmin, __shfl_xor(lmin, off));
        lmax = fmaxf(lmax, __shfl_xor(lmax, off));
    }
    int wid = tid >> 6;
    if ((tid & 63) == 0) { red[wid] = lmin; red[8 + wid] = lmax; }
    __syncthreads();
    if (tid == 0) {
        float m0 = red[0], m1 = red[8];
        #pragma unroll
        for (int k = 1; k < 4; ++k) { m0 = fminf(m0, red[k]); m1 = fmaxf(m1, red[8 + k]); }
        atomicMin(&mnbuf[img], __float_as_int(m0));
        atomicMax(&mxbuf[img], __float_as_int(m1));
    }
}

// ---------------- stage 2: normalize + sigmoid + multiply ----------------
__global__ __launch_bounds__(256) void stego_stage2(
    const float* __restrict__ x, const float* __restrict__ rho,
    const int* __restrict__ mnbuf, const int* __restrict__ mxbuf,
    float* __restrict__ out)
{
    int idx = blockIdx.x * 256 + threadIdx.x;
    int img = idx >> 18;
    int pos = idx & (IMG * IMG - 1);
    int i = pos >> 9, j = pos & 511;
    float mn = __int_as_float(mnbuf[img]);
    float mx = __int_as_float(mxbuf[img]);
    float r = rho[((size_t)img << 18) + (size_t)(((i - 1) & 511) << 9) + ((j - 1) & 511)];
    float rn = (r - mn) / (mx - mn + 1e-8f);
    float score = 1.0f / (1.0f + expf(rn - 1.0f));   // sigmoid(1 - rn)
    out[idx] = x[idx] * score;
}

extern "C" void kernel_launch(void* const* d_in, const int* in_sizes, int n_in,
                              void* d_out, int out_size, void* d_ws, size_t ws_size,
                              hipStream_t stream) {
    const float* x    = (const float*)d_in[0];
    const float* hpdf = (const float*)d_in[1];
    float* out = (float*)d_out;

    float* rho  = (float*)d_ws;
    int* mnbuf  = (int*)((char*)d_ws + (size_t)NIMG * IMG * IMG * sizeof(float));
    int* mxbuf  = mnbuf + NIMG;

    hipLaunchKernelGGL(stego_init, dim3(1), dim3(64), 0, stream, mnbuf, mxbuf);
    hipLaunchKernelGGL(stego_stage1, dim3(IMG / TS, IMG / TS, NIMG), dim3(256), 0, stream,
                       x, hpdf, rho, mnbuf, mxbuf);
    const int total = NIMG * IMG * IMG;
    hipLaunchKernelGGL(stego_stage2, dim3(total / 256), dim3(256), 0, stream,
                       x, rho, mnbuf, mxbuf, out);
}

// Round 3
// 203.494 us; speedup vs baseline: 1.3188x; 1.0176x over previous
//
#include <hip/hip_runtime.h>
#include <math.h>

#define IMG  512
#define NIMG 24            // 8*3 depthwise-independent images
#define TS   32
#define SB   68            // LDS row stride: ≡4 (mod 32) -> b128 reads at full LDS bw, rows 16B-aligned

// ---------------- init per-image min/max slots ----------------
__global__ void stego_init(int* __restrict__ mn, int* __restrict__ mx) {
    int t = threadIdx.x;
    if (t < NIMG) {
        mn[t] = __float_as_int(1e38f);  // rho >= 0, int ordering valid for nonneg floats
        mx[t] = 0;
    }
}

// coefficient modes (h = hpdf, lpdf[v] = (-1)^v h[15-v]):
// 0: h[v]   1: lpdf[v]   2: |h[v]|   3: |h[15-v]|
template<int MODE>
__device__ __forceinline__ float coef(const float* __restrict__ h, int v) {
    if (MODE == 0) return h[v];
    if (MODE == 1) return (v & 1) ? -h[15 - v] : h[15 - v];
    if (MODE == 2) return fabsf(h[v]);
    return fabsf(h[15 - v]);
}

template<int NW>   // load NW float4s (16B-aligned LDS pointer) into scalar window
__device__ __forceinline__ void load_win(const float* __restrict__ p, float* w) {
    #pragma unroll
    for (int k = 0; k < NW; ++k) {
        float4 t = ((const float4*)p)[k];
        w[4*k+0] = t.x; w[4*k+1] = t.y; w[4*k+2] = t.z; w[4*k+3] = t.w;
    }
}

// stage B: vertical conv done as horizontal pass over T' rows; writes R (normal layout) transposed.
template<int MODE>
__device__ __forceinline__ void stageB(const float* __restrict__ Tp, float* __restrict__ R,
                                       const float* __restrict__ h, int tid) {
    const int jr = tid & 63, s = tid >> 6;
    if (jr < 48) {
        const float* p = Tp + jr * SB + s * 12;
        float w[28];
        load_win<7>(p, w);
        #pragma unroll
        for (int o = 0; o < 12; ++o) {
            float acc = 0.f;
            #pragma unroll
            for (int v = 0; v < 16; ++v) acc = fmaf(coef<MODE>(h, v), w[o + v], acc);
            R[(s * 12 + o) * SB + jr] = fabsf(acc);
        }
    }
}

// stage C: horizontal conv over R rows; writes U' (transposed).
template<int MODE>
__device__ __forceinline__ void stageC(const float* __restrict__ R, float* __restrict__ U,
                                       const float* __restrict__ h, int tid) {
    const int i = tid & 63, s = tid >> 6;
    if (i < 47) {
        const float* p = R + i * SB + s * 8;
        float w[24];
        load_win<6>(p, w);
        #pragma unroll
        for (int o = 0; o < 8; ++o) {
            float acc = 0.f;
            #pragma unroll
            for (int v = 0; v < 16; ++v) acc = fmaf(coef<MODE>(h, v), w[o + v], acc);
            U[(s * 8 + o) * SB + i] = acc;
        }
    }
}

// stage D: vertical conv as horizontal pass over U' rows; rho += 1/xi in registers.
template<int MODE>
__device__ __forceinline__ void stageD(const float* __restrict__ U, const float* __restrict__ h,
                                       int tid, float rho[4]) {
    const int col = tid & 31, sg = tid >> 5;
    const float* p = U + col * SB + sg * 4;
    float w[20];
    load_win<5>(p, w);
    #pragma unroll
    for (int o = 0; o < 4; ++o) {
        float acc = 0.f;
        #pragma unroll
        for (int v = 0; v < 16; ++v) acc = fmaf(coef<MODE>(h, v), w[o + v], acc);
        rho[o] += __builtin_amdgcn_rcpf(acc);
    }
}

// ---------------- stage 1: rho + per-image min/max ----------------
__global__ __launch_bounds__(256) void stego_stage1(
    const float* __restrict__ x, const float* __restrict__ hpdf,
    float* __restrict__ rho_out, int* __restrict__ mnbuf, int* __restrict__ mxbuf)
{
    __shared__ __align__(16) float BufX[64 * SB];   // X (62x62), then R (48x68)
    __shared__ __align__(16) float BufL[48 * SB];   // T_L' (48x64 used), then U' (32x47 used)
    __shared__ __align__(16) float BufH[48 * SB];   // T_H' (kept across LH and HH)
    __shared__ float red[16];

    const int tid = threadIdx.x;
    const int Oj = blockIdx.x * TS;
    const int Oi = blockIdx.y * TS;
    const int img = blockIdx.z;
    const float* ximg = x + (size_t)img * IMG * IMG;

    // load reflect-padded 62x62 tile into BufX (64x68, zeros elsewhere)
    for (int e = tid; e < 64 * SB; e += 256) {
        int i = e / SB, j = e - i * SB;
        float v = 0.f;
        if (i < 62 && j < 62) {
            int gi = Oi + i - 15; gi = (gi < 0) ? -gi : ((gi >= IMG) ? 2 * IMG - 2 - gi : gi);
            int gj = Oj + j - 15; gj = (gj < 0) ? -gj : ((gj >= IMG) ? 2 * IMG - 2 - gj : gj);
            v = ximg[gi * IMG + gj];
        }
        BufX[e] = v;
    }
    __syncthreads();

    // stage A (fused): one window read, both hconvs (L -> BufL, H -> BufH), transposed writes
    {
        const int line = tid & 63, s = tid >> 6;
        const float* p = BufX + line * SB + s * 12;
        float w[28];
        load_win<7>(p, w);
        #pragma unroll
        for (int o = 0; o < 12; ++o) {
            float aL = 0.f, aH = 0.f;
            #pragma unroll
            for (int v = 0; v < 16; ++v) {
                aL = fmaf(coef<1>(hpdf, v), w[o + v], aL);
                aH = fmaf(coef<0>(hpdf, v), w[o + v], aH);
            }
            BufL[(s * 12 + o) * SB + line] = aL;
            BufH[(s * 12 + o) * SB + line] = aH;
        }
    }
    __syncthreads();

    float rho[4] = {0.f, 0.f, 0.f, 0.f};

    // ---- HL: b=L (T_L), a=H (mode0), b2=|h| (mode2), a2=|h rev| (mode3) ----
    stageB<0>(BufL, BufX, hpdf, tid);  __syncthreads();
    stageC<2>(BufX, BufL, hpdf, tid);  __syncthreads();
    stageD<3>(BufL, hpdf, tid, rho);
    // ---- LH: b=H (T_H), a=L (mode1), b2=|h rev| (mode3), a2=|h| (mode2) ----
    stageB<1>(BufH, BufX, hpdf, tid);  __syncthreads();   // also fences D's BufL reads before C rewrites
    stageC<3>(BufX, BufL, hpdf, tid);  __syncthreads();
    stageD<2>(BufL, hpdf, tid, rho);
    // ---- HH: b=H (T_H), a=H (mode0), b2=|h rev| (mode3), a2=|h rev| (mode3) ----
    stageB<0>(BufH, BufX, hpdf, tid);  __syncthreads();
    stageC<3>(BufX, BufL, hpdf, tid);  __syncthreads();
    stageD<3>(BufL, hpdf, tid, rho);

    // finalize: clamp/NaN, store rho, per-image min/max (I0=(tid>>5)*4, J=tid&31)
    const int J  = tid & 31;
    const int I0 = (tid >> 5) * 4;
    float lmin = 1e38f, lmax = 0.f;
    const size_t rbase = (size_t)img * IMG * IMG;
    #pragma unroll
    for (int t = 0; t < 4; ++t) {
        float r = rho[t];
        r = isnan(r) ? 1e10f : fminf(r, 1e10f);
        rho_out[rbase + (size_t)(Oi + I0 + t) * IMG + (Oj + J)] = r;
        lmin = fminf(lmin, r);
        lmax = fmaxf(lmax, r);
    }

    #pragma unroll
    for (int off = 32; off >= 1; off >>= 1) {
        lmin = fminf(lmin, __shfl_xor(lmin, off));
        lmax = fmaxf(lmax, __shfl_xor(lmax, off));
    }
    int wid = tid >> 6;
    if ((tid & 63) == 0) { red[wid] = lmin; red[8 + wid] = lmax; }
    __syncthreads();
    if (tid == 0) {
        float m0 = red[0], m1 = red[8];
        #pragma unroll
        for (int k = 1; k < 4; ++k) { m0 = fminf(m0, red[k]); m1 = fmaxf(m1, red[8 + k]); }
        atomicMin(&mnbuf[img], __float_as_int(m0));
        atomicMax(&mxbuf[img], __float_as_int(m1));
    }
}

// ---------------- stage 2: normalize + sigmoid + multiply (float4) ----------------
__global__ __launch_bounds__(256) void stego_stage2(
    const float* __restrict__ x, const float* __restrict__ rho,
    const int* __restrict__ mnbuf, const int* __restrict__ mxbuf,
    float* __restrict__ out)
{
    int t = blockIdx.x * 256 + threadIdx.x;      // group of 4 elements
    int img = t >> 16;                           // 65536 groups per image
    int pos4 = t & 65535;
    int i  = pos4 >> 7;                          // row
    int j0 = (pos4 & 127) << 2;                  // first col of group
    const size_t ibase = (size_t)img << 18;
    float mn  = __int_as_float(mnbuf[img]);
    float mx  = __int_as_float(mxbuf[img]);
    float inv = __builtin_amdgcn_rcpf(mx - mn + 1e-8f);

    int ri = (i - 1) & 511;
    const float* rrow = rho + ibase + ((size_t)ri << 9);
    float4 rv  = *(const float4*)(rrow + j0);
    float  rm1 = rrow[(j0 - 1) & 511];           // wrapped left neighbor (same row)
    float r[4] = {rm1, rv.x, rv.y, rv.z};

    float4 xv = *(const float4*)(x + ibase + ((size_t)i << 9) + j0);
    float xs[4] = {xv.x, xv.y, xv.z, xv.w};
    float os[4];
    #pragma unroll
    for (int k = 0; k < 4; ++k) {
        float rn = (r[k] - mn) * inv;
        os[k] = xs[k] * __builtin_amdgcn_rcpf(1.f + __expf(rn - 1.f));  // x * sigmoid(1-rn)
    }
    float4 ov = {os[0], os[1], os[2], os[3]};
    *(float4*)(out + ibase + ((size_t)i << 9) + j0) = ov;
}

extern "C" void kernel_launch(void* const* d_in, const int* in_sizes, int n_in,
                              void* d_out, int out_size, void* d_ws, size_t ws_size,
                              hipStream_t stream) {
    const float* x    = (const float*)d_in[0];
    const float* hpdf = (const float*)d_in[1];
    float* out = (float*)d_out;

    float* rho  = (float*)d_ws;
    int* mnbuf  = (int*)((char*)d_ws + (size_t)NIMG * IMG * IMG * sizeof(float));
    int* mxbuf  = mnbuf + NIMG;

    hipLaunchKernelGGL(stego_init, dim3(1), dim3(64), 0, stream, mnbuf, mxbuf);
    hipLaunchKernelGGL(stego_stage1, dim3(IMG / TS, IMG / TS, NIMG), dim3(256), 0, stream,
                       x, hpdf, rho, mnbuf, mxbuf);
    const int total4 = NIMG * IMG * IMG / 4;
    hipLaunchKernelGGL(stego_stage2, dim3(total4 / 256), dim3(256), 0, stream,
                       x, rho, mnbuf, mxbuf, out);
}

// Round 4
// 153.180 us; speedup vs baseline: 1.7519x; 1.3285x over previous
//
#include <hip/hip_runtime.h>
#include <math.h>

#define IMG   512
#define NIMG  24
#define SX    68        // X/R row stride (mod 32 == 4 -> conflict-free b128)
#define STP   100       // T'/U' row stride (mod 32 == 4)
#define XROWS 94
#define XOFF  0         // X: 94*68 = 6392 floats; R aliases (80*68=5440)
#define TLOFF 6392      // T_L': 48*100 = 4800; U' aliases (32*100=3200)
#define THOFF 11192     // T_H': 48*100 = 4800
#define POOLF 15992     // 63,968 B -> 2 blocks/CU

// coefficient modes (h = hpdf, lpdf[v] = (-1)^v h[15-v]):
// 0: h[v]   1: lpdf[v]   2: |h[v]|   3: |h[15-v]|
template<int MODE>
__device__ __forceinline__ float coef(const float* __restrict__ h, int v) {
    if (MODE == 0) return h[v];
    if (MODE == 1) return (v & 1) ? -h[15 - v] : h[15 - v];
    if (MODE == 2) return fabsf(h[v]);
    return fabsf(h[15 - v]);
}

__device__ __forceinline__ int refl(int g) {
    return g < 0 ? -g : (g >= IMG ? 2 * IMG - 2 - g : g);
}

template<int NW>   // NW aligned float4 LDS loads -> scalar window
__device__ __forceinline__ void load_win(const float* __restrict__ p, float* w) {
    #pragma unroll
    for (int k = 0; k < NW; ++k) {
        float4 t = ((const float4*)p)[k];
        w[4*k] = t.x; w[4*k+1] = t.y; w[4*k+2] = t.z; w[4*k+3] = t.w;
    }
}

// B: vconv over T' rows (LEN=8), writes R normal layout. 480 units.
template<int MODE>
__device__ __forceinline__ void stageB(const float* __restrict__ pt, float* __restrict__ pr,
                                       const float* __restrict__ h, int tid) {
    if (tid < 480) {
        int s = tid / 48, jr = tid - s * 48;
        float w[24];
        load_win<6>(pt + jr * STP + s * 8, w);
        #pragma unroll
        for (int o = 0; o < 8; ++o) {
            float acc = 0.f;
            #pragma unroll
            for (int v = 0; v < 16; ++v) acc = fmaf(coef<MODE>(h, v), w[o + v], acc);
            pr[(s * 8 + o) * SX + jr] = fabsf(acc);
        }
    }
}

// C: hconv over R rows (LEN=8), writes U' transposed. 316 units.
template<int MODE>
__device__ __forceinline__ void stageC(const float* __restrict__ pr, float* __restrict__ pu,
                                       const float* __restrict__ h, int tid) {
    if (tid < 316) {
        int s = tid / 79, i = tid - s * 79;
        float w[24];
        load_win<6>(pr + i * SX + s * 8, w);
        #pragma unroll
        for (int o = 0; o < 8; ++o) {
            float acc = 0.f;
            #pragma unroll
            for (int v = 0; v < 16; ++v) acc = fmaf(coef<MODE>(h, v), w[o + v], acc);
            pu[(s * 8 + o) * STP + i] = acc;
        }
    }
}

// D: vconv over U' rows (LEN=4); rho += 1/xi. All 512 threads (16 segs x 32 cols).
template<int MODE>
__device__ __forceinline__ void stageD(const float* __restrict__ pu, const float* __restrict__ h,
                                       int tid, float rho[4]) {
    int col = tid & 31, sg = tid >> 5;
    float w[20];
    load_win<5>(pu + col * STP + sg * 4, w);
    #pragma unroll
    for (int o = 0; o < 4; ++o) {
        float acc = 0.f;
        #pragma unroll
        for (int v = 0; v < 16; ++v) acc = fmaf(coef<MODE>(h, v), w[o + v], acc);
        rho[o] += __builtin_amdgcn_rcpf(acc);
    }
}

// ---------------- stage 1: rho + per-image min/max (tile 64 rows x 32 cols) ----------------
__global__ __launch_bounds__(512, 4) void stego_stage1(
    const float* __restrict__ x, const float* __restrict__ hpdf,
    float* __restrict__ rho_out, int* __restrict__ mnbuf, int* __restrict__ mxbuf)
{
    __shared__ __align__(16) float pool[POOLF];
    __shared__ float red[16];

    const int tid = threadIdx.x;
    const int Oj = blockIdx.x * 32;
    const int Oi = blockIdx.y * 64;
    const int img = blockIdx.z;
    const float* ximg = x + (size_t)img * IMG * IMG;
    const int lane = tid & 63, wid = tid >> 6;

    // ---- load X: 94 rows x 64 cols (stride 68); interior fast path (uniform branch) ----
    if (Oi >= 15 && Oi <= 433 && Oj >= 15 && Oj <= 463) {
        const float* src = ximg + (size_t)(Oi - 15) * IMG + (Oj - 15 + lane);
        #pragma unroll
        for (int k = 0; k < 12; ++k) {
            int i = wid + (k << 3);
            if (i < XROWS) pool[XOFF + i * SX + lane] = src[(size_t)i * IMG];
        }
    } else {
        int gj = refl(Oj - 15 + lane);
        #pragma unroll
        for (int k = 0; k < 12; ++k) {
            int i = wid + (k << 3);
            if (i < XROWS) {
                int gi = refl(Oi - 15 + i);
                pool[XOFF + i * SX + lane] = ximg[gi * IMG + gj];
            }
        }
    }
    __syncthreads();

    // ---- A (fused L+H): 564 units = 6 segs(LEN 8) x 94 rows; writes T_L', T_H' transposed ----
    #pragma unroll
    for (int uu = 0; uu < 2; ++uu) {
        int u = tid + uu * 512;
        if (u < 564) {
            int s = u / 94, r = u - s * 94;
            float w[24];
            load_win<6>(pool + XOFF + r * SX + s * 8, w);
            #pragma unroll
            for (int o = 0; o < 8; ++o) {
                float aL = 0.f, aH = 0.f;
                #pragma unroll
                for (int v = 0; v < 16; ++v) {
                    aL = fmaf(coef<1>(hpdf, v), w[o + v], aL);
                    aH = fmaf(coef<0>(hpdf, v), w[o + v], aH);
                }
                pool[TLOFF + (s * 8 + o) * STP + r] = aL;
                pool[THOFF + (s * 8 + o) * STP + r] = aH;
            }
        }
    }
    __syncthreads();

    float rho[4] = {0.f, 0.f, 0.f, 0.f};

    // ---- HL: B<a=H> on T_L; C<|h|>; D<|h rev|> ----
    stageB<0>(pool + TLOFF, pool + XOFF, hpdf, tid);  __syncthreads();
    stageC<2>(pool + XOFF, pool + TLOFF, hpdf, tid);  __syncthreads();
    // ---- LH: B<a=L> on T_H (runs with D of HL); C<|h rev|>; D<|h|> ----
    stageD<3>(pool + TLOFF, hpdf, tid, rho);
    stageB<1>(pool + THOFF, pool + XOFF, hpdf, tid);  __syncthreads();
    stageC<3>(pool + XOFF, pool + TLOFF, hpdf, tid);  __syncthreads();
    // ---- HH: B<a=H> on T_H (runs with D of LH); C<|h rev|>; D<|h rev|> ----
    stageD<2>(pool + TLOFF, hpdf, tid, rho);
    stageB<0>(pool + THOFF, pool + XOFF, hpdf, tid);  __syncthreads();
    stageC<3>(pool + XOFF, pool + TLOFF, hpdf, tid);  __syncthreads();
    stageD<3>(pool + TLOFF, hpdf, tid, rho);

    // ---- finalize: clamp/NaN, store rho, per-image min/max ----
    const int col = tid & 31, sg = tid >> 5;
    float lmin = 1e38f, lmax = 0.f;
    const size_t rbase = (size_t)img * IMG * IMG;
    #pragma unroll
    for (int t = 0; t < 4; ++t) {
        float r = rho[t];
        r = isnan(r) ? 1e10f : fminf(r, 1e10f);
        rho_out[rbase + (size_t)(Oi + sg * 4 + t) * IMG + (Oj + col)] = r;
        lmin = fminf(lmin, r);
        lmax = fmaxf(lmax, r);
    }
    #pragma unroll
    for (int off = 32; off >= 1; off >>= 1) {
        lmin = fminf(lmin, __shfl_xor(lmin, off));
        lmax = fmaxf(lmax, __shfl_xor(lmax, off));
    }
    if ((tid & 63) == 0) { red[wid] = lmin; red[8 + wid] = lmax; }
    __syncthreads();
    if (tid == 0) {
        float m0 = red[0], m1 = red[8];
        #pragma unroll
        for (int k = 1; k < 8; ++k) { m0 = fminf(m0, red[k]); m1 = fmaxf(m1, red[8 + k]); }
        atomicMin(&mnbuf[img], __float_as_int(m0));
        atomicMax(&mxbuf[img], __float_as_int(m1));
    }
}

// ---------------- stage 2: normalize + sigmoid + multiply (float4) ----------------
__global__ __launch_bounds__(256) void stego_stage2(
    const float* __restrict__ x, const float* __restrict__ rho,
    const int* __restrict__ mnbuf, const int* __restrict__ mxbuf,
    float* __restrict__ out)
{
    int t = blockIdx.x * 256 + threadIdx.x;      // group of 4 elements
    int img = t >> 16;
    int pos4 = t & 65535;
    int i  = pos4 >> 7;
    int j0 = (pos4 & 127) << 2;
    const size_t ibase = (size_t)img << 18;
    float mn  = __int_as_float(mnbuf[img]);
    float mx  = __int_as_float(mxbuf[img]);
    float inv = __builtin_amdgcn_rcpf(mx - mn + 1e-8f);

    int ri = (i - 1) & 511;
    const float* rrow = rho + ibase + ((size_t)ri << 9);
    float4 rv  = *(const float4*)(rrow + j0);
    float  rm1 = rrow[(j0 - 1) & 511];
    float r[4] = {rm1, rv.x, rv.y, rv.z};

    float4 xv = *(const float4*)(x + ibase + ((size_t)i << 9) + j0);
    float xs[4] = {xv.x, xv.y, xv.z, xv.w};
    float os[4];
    #pragma unroll
    for (int k = 0; k < 4; ++k) {
        float rn = (r[k] - mn) * inv;
        os[k] = xs[k] * __builtin_amdgcn_rcpf(1.f + __expf(rn - 1.f));  // x * sigmoid(1-rn)
    }
    float4 ov = {os[0], os[1], os[2], os[3]};
    *(float4*)(out + ibase + ((size_t)i << 9) + j0) = ov;
}

extern "C" void kernel_launch(void* const* d_in, const int* in_sizes, int n_in,
                              void* d_out, int out_size, void* d_ws, size_t ws_size,
                              hipStream_t stream) {
    const float* x    = (const float*)d_in[0];
    const float* hpdf = (const float*)d_in[1];
    float* out = (float*)d_out;

    float* rho  = (float*)d_ws;
    int* mnbuf  = (int*)((char*)d_ws + (size_t)NIMG * IMG * IMG * sizeof(float));
    int* mxbuf  = mnbuf + NIMG;

    // init: 0x7F7F7F7F = 3.39e38 (min slots), 0 (max slots) — valid since rho >= 0
    hipMemsetAsync((void*)mnbuf, 0x7F, NIMG * sizeof(int), stream);
    hipMemsetAsync((void*)mxbuf, 0x00, NIMG * sizeof(int), stream);

    hipLaunchKernelGGL(stego_stage1, dim3(IMG / 32, IMG / 64, NIMG), dim3(512), 0, stream,
                       x, hpdf, rho, mnbuf, mxbuf);
    const int total4 = NIMG * IMG * IMG / 4;
    hipLaunchKernelGGL(stego_stage2, dim3(total4 / 256), dim3(256), 0, stream,
                       x, rho, mnbuf, mxbuf, out);
}

// Round 5
// 148.204 us; speedup vs baseline: 1.8108x; 1.0336x over previous
//
#include <hip/hip_runtime.h>
#include <math.h>

#define IMG   512
#define NIMG  24
#define SX    68        // X/R fp32 row stride (mod 32 == 4 -> conflict-free b128)
#define STPH  100       // T'/U' fp16 row stride in halfs (200 B/row; 2-way bank alias = free)
#define XROWS 94

typedef _Float16 h4 __attribute__((ext_vector_type(4)));

// coefficient modes (h = hpdf, lpdf[v] = (-1)^v h[15-v]):
// 0: h[v]   1: lpdf[v]   2: |h[v]|   3: |h[15-v]|
template<int MODE>
__device__ __forceinline__ float coef(const float* __restrict__ h, int v) {
    if (MODE == 0) return h[v];
    if (MODE == 1) return (v & 1) ? -h[15 - v] : h[15 - v];
    if (MODE == 2) return fabsf(h[v]);
    return fabsf(h[15 - v]);
}

__device__ __forceinline__ int refl(int g) {
    return g < 0 ? -g : (g >= IMG ? 2 * IMG - 2 - g : g);
}

template<int NW>   // NW aligned float4 LDS loads -> scalar window
__device__ __forceinline__ void load_win(const float* __restrict__ p, float* w) {
    #pragma unroll
    for (int k = 0; k < NW; ++k) {
        float4 t = ((const float4*)p)[k];
        w[4*k] = t.x; w[4*k+1] = t.y; w[4*k+2] = t.z; w[4*k+3] = t.w;
    }
}

template<int N4>   // N4 aligned half4 (b64) LDS loads -> fp32 scalar window
__device__ __forceinline__ void load_win_h(const _Float16* __restrict__ p, float* w) {
    #pragma unroll
    for (int k = 0; k < N4; ++k) {
        h4 t = ((const h4*)p)[k];
        w[4*k]   = (float)t.x; w[4*k+1] = (float)t.y;
        w[4*k+2] = (float)t.z; w[4*k+3] = (float)t.w;
    }
}

// B: vconv over T' (fp16) rows (LEN=8), writes R fp32 normal layout. 480 units.
template<int MODE>
__device__ __forceinline__ void stageB(const _Float16* __restrict__ pt, float* __restrict__ pr,
                                       const float* __restrict__ h, int tid) {
    if (tid < 480) {
        int s = tid / 48, jr = tid - s * 48;
        float w[24];
        load_win_h<6>(pt + jr * STPH + s * 8, w);
        #pragma unroll
        for (int o = 0; o < 8; ++o) {
            float acc = 0.f;
            #pragma unroll
            for (int v = 0; v < 16; ++v) acc = fmaf(coef<MODE>(h, v), w[o + v], acc);
            pr[(s * 8 + o) * SX + jr] = fabsf(acc);
        }
    }
}

// C: hconv over R (fp32) rows (LEN=8), writes U' fp16 transposed. 316 units.
template<int MODE>
__device__ __forceinline__ void stageC(const float* __restrict__ pr, _Float16* __restrict__ pu,
                                       const float* __restrict__ h, int tid) {
    if (tid < 316) {
        int s = tid / 79, i = tid - s * 79;
        float w[24];
        load_win<6>(pr + i * SX + s * 8, w);
        #pragma unroll
        for (int o = 0; o < 8; ++o) {
            float acc = 0.f;
            #pragma unroll
            for (int v = 0; v < 16; ++v) acc = fmaf(coef<MODE>(h, v), w[o + v], acc);
            pu[(s * 8 + o) * STPH + i] = (_Float16)acc;
        }
    }
}

// D: vconv over U' (fp16) rows (LEN=4); rho += 1/xi. All 512 threads.
template<int MODE>
__device__ __forceinline__ void stageD(const _Float16* __restrict__ pu, const float* __restrict__ h,
                                       int tid, float rho[4]) {
    int col = tid & 31, sg = tid >> 5;
    float w[20];
    load_win_h<5>(pu + col * STPH + sg * 4, w);
    #pragma unroll
    for (int o = 0; o < 4; ++o) {
        float acc = 0.f;
        #pragma unroll
        for (int v = 0; v < 16; ++v) acc = fmaf(coef<MODE>(h, v), w[o + v], acc);
        rho[o] += __builtin_amdgcn_rcpf(acc);
    }
}

// ---------------- stage 1: rho + per-block min/max (tile 64 rows x 32 cols) ----------------
__global__ __launch_bounds__(512, 6) void stego_stage1(
    const float* __restrict__ x, const float* __restrict__ hpdf,
    float* __restrict__ rho_out, float2* __restrict__ bmm)
{
    __shared__ __align__(16) float sX[XROWS * SX];       // X (94x68), then R (80x68)
    __shared__ __align__(16) _Float16 sTL[48 * STPH];    // T_L', then U'
    __shared__ __align__(16) _Float16 sTH[48 * STPH];    // T_H' (kept across LH and HH)
    __shared__ float red[16];

    const int tid = threadIdx.x;
    const int Oj = blockIdx.x * 32;
    const int Oi = blockIdx.y * 64;
    const int img = blockIdx.z;
    const float* ximg = x + (size_t)img * IMG * IMG;
    const int lane = tid & 63, wid = tid >> 6;

    // ---- load X: 94 rows x 64 cols (stride 68); interior fast path (uniform branch) ----
    if (Oi >= 15 && Oi <= 433 && Oj >= 15 && Oj <= 463) {
        const float* src = ximg + (size_t)(Oi - 15) * IMG + (Oj - 15 + lane);
        #pragma unroll
        for (int k = 0; k < 12; ++k) {
            int i = wid + (k << 3);
            if (i < XROWS) sX[i * SX + lane] = src[(size_t)i * IMG];
        }
    } else {
        int gj = refl(Oj - 15 + lane);
        #pragma unroll
        for (int k = 0; k < 12; ++k) {
            int i = wid + (k << 3);
            if (i < XROWS) {
                int gi = refl(Oi - 15 + i);
                sX[i * SX + lane] = ximg[gi * IMG + gj];
            }
        }
    }
    __syncthreads();

    // ---- A (fused L+H): 564 units = 6 segs(LEN 8) x 94 rows; T_L', T_H' transposed fp16 ----
    #pragma unroll
    for (int uu = 0; uu < 2; ++uu) {
        int u = tid + uu * 512;
        if (u < 564) {
            int s = u / 94, r = u - s * 94;
            float w[24];
            load_win<6>(sX + r * SX + s * 8, w);
            #pragma unroll
            for (int o = 0; o < 8; ++o) {
                float aL = 0.f, aH = 0.f;
                #pragma unroll
                for (int v = 0; v < 16; ++v) {
                    aL = fmaf(coef<1>(hpdf, v), w[o + v], aL);
                    aH = fmaf(coef<0>(hpdf, v), w[o + v], aH);
                }
                sTL[(s * 8 + o) * STPH + r] = (_Float16)aL;
                sTH[(s * 8 + o) * STPH + r] = (_Float16)aH;
            }
        }
    }
    __syncthreads();

    float rho[4] = {0.f, 0.f, 0.f, 0.f};

    // ---- HL: B<a=H> on T_L; C<|h|>; D<|h rev|> ----
    stageB<0>(sTL, sX, hpdf, tid);  __syncthreads();
    stageC<2>(sX, sTL, hpdf, tid);  __syncthreads();
    // ---- LH: D of HL runs with B<a=L> on T_H ----
    stageD<3>(sTL, hpdf, tid, rho);
    stageB<1>(sTH, sX, hpdf, tid);  __syncthreads();
    stageC<3>(sX, sTL, hpdf, tid);  __syncthreads();
    // ---- HH: D of LH runs with B<a=H> on T_H ----
    stageD<2>(sTL, hpdf, tid, rho);
    stageB<0>(sTH, sX, hpdf, tid);  __syncthreads();
    stageC<3>(sX, sTL, hpdf, tid);  __syncthreads();
    stageD<3>(sTL, hpdf, tid, rho);

    // ---- finalize: clamp/NaN, store rho, per-block min/max (no atomics) ----
    const int col = tid & 31, sg = tid >> 5;
    float lmin = 1e38f, lmax = 0.f;
    const size_t rbase = (size_t)img * IMG * IMG;
    #pragma unroll
    for (int t = 0; t < 4; ++t) {
        float r = rho[t];
        r = isnan(r) ? 1e10f : fminf(r, 1e10f);
        rho_out[rbase + (size_t)(Oi + sg * 4 + t) * IMG + (Oj + col)] = r;
        lmin = fminf(lmin, r);
        lmax = fmaxf(lmax, r);
    }
    #pragma unroll
    for (int off = 32; off >= 1; off >>= 1) {
        lmin = fminf(lmin, __shfl_xor(lmin, off));
        lmax = fmaxf(lmax, __shfl_xor(lmax, off));
    }
    if ((tid & 63) == 0) { red[wid] = lmin; red[8 + wid] = lmax; }
    __syncthreads();
    if (tid == 0) {
        float m0 = red[0], m1 = red[8];
        #pragma unroll
        for (int k = 1; k < 8; ++k) { m0 = fminf(m0, red[k]); m1 = fmaxf(m1, red[8 + k]); }
        bmm[(img << 7) + blockIdx.y * 16 + blockIdx.x] = make_float2(m0, m1);
    }
}

// ---------------- stage 2: reduce block minmax + normalize + sigmoid + multiply ----------------
__global__ __launch_bounds__(256) void stego_stage2(
    const float* __restrict__ x, const float* __restrict__ rho,
    const float2* __restrict__ bmm, float* __restrict__ out)
{
    __shared__ float sred[8];
    const int tid = threadIdx.x;
    const int t = blockIdx.x * 256 + tid;      // group of 4 elements
    const int img = t >> 16;                   // constant per block (1024 px/block)

    // prologue: reduce this image's 128 per-block (min,max) pairs
    float lmn = 1e38f, lmx = 0.f;
    if (tid < 128) { float2 p = bmm[(img << 7) + tid]; lmn = p.x; lmx = p.y; }
    #pragma unroll
    for (int off = 32; off >= 1; off >>= 1) {
        lmn = fminf(lmn, __shfl_xor(lmn, off));
        lmx = fmaxf(lmx, __shfl_xor(lmx, off));
    }
    if (tid < 128 && (tid & 63) == 0) { sred[tid >> 6] = lmn; sred[4 + (tid >> 6)] = lmx; }
    __syncthreads();
    const float mn = fminf(sred[0], sred[1]);
    const float mx = fmaxf(sred[4], sred[5]);
    const float inv = __builtin_amdgcn_rcpf(mx - mn + 1e-8f);

    int pos4 = t & 65535;
    int i  = pos4 >> 7;
    int j0 = (pos4 & 127) << 2;
    const size_t ibase = (size_t)img << 18;

    int ri = (i - 1) & 511;
    const float* rrow = rho + ibase + ((size_t)ri << 9);
    float4 rv  = *(const float4*)(rrow + j0);
    float  rm1 = rrow[(j0 - 1) & 511];
    float r[4] = {rm1, rv.x, rv.y, rv.z};

    float4 xv = *(const float4*)(x + ibase + ((size_t)i << 9) + j0);
    float xs[4] = {xv.x, xv.y, xv.z, xv.w};
    float os[4];
    #pragma unroll
    for (int k = 0; k < 4; ++k) {
        float rn = (r[k] - mn) * inv;
        os[k] = xs[k] * __builtin_amdgcn_rcpf(1.f + __expf(rn - 1.f));  // x * sigmoid(1-rn)
    }
    float4 ov = {os[0], os[1], os[2], os[3]};
    *(float4*)(out + ibase + ((size_t)i << 9) + j0) = ov;
}

extern "C" void kernel_launch(void* const* d_in, const int* in_sizes, int n_in,
                              void* d_out, int out_size, void* d_ws, size_t ws_size,
                              hipStream_t stream) {
    const float* x    = (const float*)d_in[0];
    const float* hpdf = (const float*)d_in[1];
    float* out = (float*)d_out;

    float* rho  = (float*)d_ws;                                          // 24*512*512 fp32
    float2* bmm = (float2*)((char*)d_ws + (size_t)NIMG * IMG * IMG * 4); // 24*128 float2

    hipLaunchKernelGGL(stego_stage1, dim3(IMG / 32, IMG / 64, NIMG), dim3(512), 0, stream,
                       x, hpdf, rho, bmm);
    const int total4 = NIMG * IMG * IMG / 4;
    hipLaunchKernelGGL(stego_stage2, dim3(total4 / 256), dim3(256), 0, stream,
                       x, rho, bmm, out);
}

// Round 7
// 141.946 us; speedup vs baseline: 1.8906x; 1.0441x over previous
//
#include <hip/hip_runtime.h>
#include <math.h>

#define IMG   512
#define NIMG  24
#define SXH   72     // X fp16 stride (halfs) = 36 dw ≡ 4 mod 8 -> conflict-free lane-strided b128
#define STH   104    // T' stride = 52 dw ≡ 4 mod 8
#define SRH   56     // R  stride = 28 dw ≡ 4 mod 8
#define SUH   88     // U' stride = 44 dw (b64 reads, 2-way alias = free)
#define XROWS 94
#define UOFF  4480   // U' offset (halfs) inside pool1 (R = 80*56 = 4480)
#define P1SZ  7296   // pool1 halfs: max(X 94*72=6768, R+U' 4480+2816=7296)
#define TSZ   (48 * STH)

typedef _Float16 half2t __attribute__((ext_vector_type(2)));

__device__ __forceinline__ half2t bch2(unsigned u) {
    union { unsigned u; half2t h; } c; c.u = u; return c.h;
}

__device__ __forceinline__ unsigned pkrtz(float a, float b) {
    union { __fp16 __attribute__((ext_vector_type(2))) v; unsigned u; } c;
    c.v = __builtin_amdgcn_cvt_pkrtz(a, b);
    return c.u;
}

// coefficient modes (h = hpdf, lpdf[v] = (-1)^v h[15-v]):
// 0: h[v]   1: lpdf[v]   2: |h[v]|   3: |h[15-v]|
template<int MODE>
__device__ __forceinline__ float coef(const float* __restrict__ h, int v) {
    if (MODE == 0) return h[v];
    if (MODE == 1) return (v & 1) ? -h[15 - v] : h[15 - v];
    if (MODE == 2) return fabsf(h[v]);
    return fabsf(h[15 - v]);
}

template<int MODE>
__device__ __forceinline__ void build_cp(const float* __restrict__ h, half2t cp[8]) {
    #pragma unroll
    for (int k = 0; k < 8; ++k) {
        half2t p;
        p.x = (_Float16)coef<MODE>(h, 2 * k);
        p.y = (_Float16)coef<MODE>(h, 2 * k + 1);
        cp[k] = p;
    }
}

__device__ __forceinline__ int refl(int g) {
    return g < 0 ? -g : (g >= IMG ? 2 * IMG - 2 - g : g);
}

// 8-output 16-tap conv via dot2; window = halfs [0,23) at 16B-aligned LDS base.
template<int MODE>
__device__ __forceinline__ void conv8(const _Float16* __restrict__ base,
                                      const float* __restrict__ h, float out[8]) {
    const uint4* b4 = (const uint4*)base;
    uint4 A0 = b4[0], A1 = b4[1], A2 = b4[2];
    unsigned up[12] = {A0.x, A0.y, A0.z, A0.w, A1.x, A1.y, A1.z, A1.w, A2.x, A2.y, A2.z, A2.w};
    half2t cp[8]; build_cp<MODE>(h, cp);
    #pragma unroll
    for (int m = 0; m < 4; ++m) {
        float acc = 0.f;
        #pragma unroll
        for (int k = 0; k < 8; ++k) acc = __builtin_amdgcn_fdot2(cp[k], bch2(up[m + k]), acc, false);
        out[2 * m] = acc;
    }
    unsigned uq[11];
    #pragma unroll
    for (int k = 0; k < 11; ++k) uq[k] = (up[k] >> 16) | (up[k + 1] << 16);
    #pragma unroll
    for (int m = 0; m < 4; ++m) {
        float acc = 0.f;
        #pragma unroll
        for (int k = 0; k < 8; ++k) acc = __builtin_amdgcn_fdot2(cp[k], bch2(uq[m + k]), acc, false);
        out[2 * m + 1] = acc;
    }
}

// fused two-filter variant for stage A (one window read, two coef sets)
__device__ __forceinline__ void conv8x2(const _Float16* __restrict__ base,
                                        const float* __restrict__ h,
                                        float oL[8], float oH[8]) {
    const uint4* b4 = (const uint4*)base;
    uint4 A0 = b4[0], A1 = b4[1], A2 = b4[2];
    unsigned up[12] = {A0.x, A0.y, A0.z, A0.w, A1.x, A1.y, A1.z, A1.w, A2.x, A2.y, A2.z, A2.w};
    half2t cL[8], cH[8];
    build_cp<1>(h, cL); build_cp<0>(h, cH);
    #pragma unroll
    for (int m = 0; m < 4; ++m) {
        float aL = 0.f, aH = 0.f;
        #pragma unroll
        for (int k = 0; k < 8; ++k) {
            half2t w = bch2(up[m + k]);
            aL = __builtin_amdgcn_fdot2(cL[k], w, aL, false);
            aH = __builtin_amdgcn_fdot2(cH[k], w, aH, false);
        }
        oL[2 * m] = aL; oH[2 * m] = aH;
    }
    unsigned uq[11];
    #pragma unroll
    for (int k = 0; k < 11; ++k) uq[k] = (up[k] >> 16) | (up[k + 1] << 16);
    #pragma unroll
    for (int m = 0; m < 4; ++m) {
        float aL = 0.f, aH = 0.f;
        #pragma unroll
        for (int k = 0; k < 8; ++k) {
            half2t w = bch2(uq[m + k]);
            aL = __builtin_amdgcn_fdot2(cL[k], w, aL, false);
            aH = __builtin_amdgcn_fdot2(cH[k], w, aH, false);
        }
        oL[2 * m + 1] = aL; oH[2 * m + 1] = aH;
    }
}

// 4-output conv for stage D; window halfs [0,20) at 8B-aligned base.
template<int MODE>
__device__ __forceinline__ void conv4(const _Float16* __restrict__ base,
                                      const float* __restrict__ h, float out[4]) {
    const uint2* b2 = (const uint2*)base;
    unsigned up[10];
    #pragma unroll
    for (int k = 0; k < 5; ++k) { uint2 t = b2[k]; up[2 * k] = t.x; up[2 * k + 1] = t.y; }
    half2t cp[8]; build_cp<MODE>(h, cp);
    #pragma unroll
    for (int m = 0; m < 2; ++m) {
        float acc = 0.f;
        #pragma unroll
        for (int k = 0; k < 8; ++k) acc = __builtin_amdgcn_fdot2(cp[k], bch2(up[m + k]), acc, false);
        out[2 * m] = acc;
    }
    unsigned uq[9];
    #pragma unroll
    for (int k = 0; k < 9; ++k) uq[k] = (up[k] >> 16) | (up[k + 1] << 16);
    #pragma unroll
    for (int m = 0; m < 2; ++m) {
        float acc = 0.f;
        #pragma unroll
        for (int k = 0; k < 8; ++k) acc = __builtin_amdgcn_fdot2(cp[k], bch2(uq[m + k]), acc, false);
        out[2 * m + 1] = acc;
    }
}

// B: vconv over T' rows (8 out rows x 48 cols each unit); writes R fp16. 480 units.
template<int MODE>
__device__ __forceinline__ void stageB(const _Float16* __restrict__ pt, _Float16* __restrict__ pr,
                                       const float* __restrict__ h, int tid) {
    if (tid < 480) {
        int s = tid / 48, jr = tid - s * 48;
        float o[8]; conv8<MODE>(pt + jr * STH + s * 8, h, o);
        #pragma unroll
        for (int k = 0; k < 8; ++k) pr[(s * 8 + k) * SRH + jr] = (_Float16)fabsf(o[k]);
    }
}

// C: hconv over R rows; writes U' transposed fp16. 316 units.
template<int MODE>
__device__ __forceinline__ void stageC(const _Float16* __restrict__ pr, _Float16* __restrict__ pu,
                                       const float* __restrict__ h, int tid) {
    if (tid < 316) {
        int s = tid / 79, i = tid - s * 79;
        float o[8]; conv8<MODE>(pr + i * SRH + s * 8, h, o);
        #pragma unroll
        for (int k = 0; k < 8; ++k) pu[(s * 8 + k) * SUH + i] = (_Float16)o[k];
    }
}

// D: vconv over U' rows (LEN=4); rho += 1/xi. All 512 threads.
template<int MODE>
__device__ __forceinline__ void stageD(const _Float16* __restrict__ pu, const float* __restrict__ h,
                                       int tid, float rho[4]) {
    int col = tid & 31, sg = tid >> 5;
    float o[4]; conv4<MODE>(pu + col * SUH + sg * 4, h, o);
    #pragma unroll
    for (int k = 0; k < 4; ++k) rho[k] += __builtin_amdgcn_rcpf(o[k]);
}

// ---------------- stage 1: rho + per-block min/max (tile 64 rows x 32 cols) ----------------
__global__ __launch_bounds__(512, 6) void stego_stage1(
    const float* __restrict__ x, const float* __restrict__ hpdf,
    float* __restrict__ rho_out, float2* __restrict__ bmm)
{
    __shared__ __align__(16) _Float16 pool1[P1SZ];   // X (94x72), then R (80x56) + U' (32x88)
    __shared__ __align__(16) _Float16 sTL[TSZ];      // T_L'
    __shared__ __align__(16) _Float16 sTH[TSZ];      // T_H' (kept across LH and HH)
    __shared__ float red[16];

    const int tid = threadIdx.x;
    const int Oj = blockIdx.x * 32;
    const int Oi = blockIdx.y * 64;
    const int img = blockIdx.z;
    const float* ximg = x + (size_t)img * IMG * IMG;

    // ---- load X as fp16: 94 rows x 64 cols; thread = (col-pair, row slice) ----
    {
        const int cp2 = tid & 31, row0 = tid >> 5;     // 32 col-pairs x 16 rows
        const int c0 = Oj - 15 + 2 * cp2;
        if (Oi >= 15 && Oi <= 433 && Oj >= 15 && Oj <= 463) {
            const float* src = ximg + (size_t)(Oi - 15) * IMG + c0;
            #pragma unroll
            for (int k = 0; k < 6; ++k) {
                int i = row0 + (k << 4);
                if (i < XROWS) {
                    float v0 = src[(size_t)i * IMG], v1 = src[(size_t)i * IMG + 1];
                    *(unsigned*)(pool1 + i * SXH + 2 * cp2) = pkrtz(v0, v1);
                }
            }
        } else {
            int gj0 = refl(c0), gj1 = refl(c0 + 1);
            #pragma unroll
            for (int k = 0; k < 6; ++k) {
                int i = row0 + (k << 4);
                if (i < XROWS) {
                    int gi = refl(Oi - 15 + i);
                    float v0 = ximg[gi * IMG + gj0], v1 = ximg[gi * IMG + gj1];
                    *(unsigned*)(pool1 + i * SXH + 2 * cp2) = pkrtz(v0, v1);
                }
            }
        }
    }
    __syncthreads();

    // ---- A (fused L+H): 564 units = 6 segs x 94 rows; writes T_L', T_H' transposed ----
    #pragma unroll
    for (int uu = 0; uu < 2; ++uu) {
        int u = tid + uu * 512;
        if (u < 564) {
            int s = u / 94, r = u - s * 94;
            float oL[8], oH[8];
            conv8x2(pool1 + r * SXH + s * 8, hpdf, oL, oH);
            #pragma unroll
            for (int o = 0; o < 8; ++o) {
                sTL[(s * 8 + o) * STH + r] = (_Float16)oL[o];
                sTH[(s * 8 + o) * STH + r] = (_Float16)oH[o];
            }
        }
    }
    __syncthreads();

    float rho[4] = {0.f, 0.f, 0.f, 0.f};
    _Float16* Rb = pool1;
    _Float16* Ub = pool1 + UOFF;

    // ---- HL: B<a=H> on T_L; C<|h|>; D<|h rev|> ----
    stageB<0>(sTL, Rb, hpdf, tid);  __syncthreads();
    stageC<2>(Rb, Ub, hpdf, tid);   __syncthreads();
    // ---- LH: D of HL runs with B<a=L> on T_H (disjoint LDS regions) ----
    stageD<3>(Ub, hpdf, tid, rho);
    stageB<1>(sTH, Rb, hpdf, tid);  __syncthreads();
    stageC<3>(Rb, Ub, hpdf, tid);   __syncthreads();
    // ---- HH: D of LH runs with B<a=H> on T_H ----
    stageD<2>(Ub, hpdf, tid, rho);
    stageB<0>(sTH, Rb, hpdf, tid);  __syncthreads();
    stageC<3>(Rb, Ub, hpdf, tid);   __syncthreads();
    stageD<3>(Ub, hpdf, tid, rho);

    // ---- finalize: clamp/NaN, store rho, per-block min/max (no atomics) ----
    const int col = tid & 31, sg = tid >> 5, wid = tid >> 6;
    float lmin = 1e38f, lmax = 0.f;
    const size_t rbase = (size_t)img * IMG * IMG;
    #pragma unroll
    for (int t = 0; t < 4; ++t) {
        float r = rho[t];
        r = isnan(r) ? 1e10f : fminf(r, 1e10f);
        rho_out[rbase + (size_t)(Oi + sg * 4 + t) * IMG + (Oj + col)] = r;
        lmin = fminf(lmin, r);
        lmax = fmaxf(lmax, r);
    }
    #pragma unroll
    for (int off = 32; off >= 1; off >>= 1) {
        lmin = fminf(lmin, __shfl_xor(lmin, off));
        lmax = fmaxf(lmax, __shfl_xor(lmax, off));
    }
    if ((tid & 63) == 0) { red[wid] = lmin; red[8 + wid] = lmax; }
    __syncthreads();
    if (tid == 0) {
        float m0 = red[0], m1 = red[8];
        #pragma unroll
        for (int k = 1; k < 8; ++k) { m0 = fminf(m0, red[k]); m1 = fmaxf(m1, red[8 + k]); }
        bmm[(img << 7) + blockIdx.y * 16 + blockIdx.x] = make_float2(m0, m1);
    }
}

// ---------------- stage 2: reduce block minmax + normalize + sigmoid + multiply (8 px/thr) ----
__global__ __launch_bounds__(256) void stego_stage2(
    const float* __restrict__ x, const float* __restrict__ rho,
    const float2* __restrict__ bmm, float* __restrict__ out)
{
    __shared__ float sred[8];
    const int tid = threadIdx.x;
    const int t = blockIdx.x * 256 + tid;      // group of 8 elements
    const int img = t >> 15;                   // 32768 groups per image

    // prologue: reduce this image's 128 per-block (min,max) pairs
    float lmn = 1e38f, lmx = 0.f;
    if (tid < 128) { float2 p = bmm[(img << 7) + tid]; lmn = p.x; lmx = p.y; }
    #pragma unroll
    for (int off = 32; off >= 1; off >>= 1) {
        lmn = fminf(lmn, __shfl_xor(lmn, off));
        lmx = fmaxf(lmx, __shfl_xor(lmx, off));
    }
    if (tid < 128 && (tid & 63) == 0) { sred[tid >> 6] = lmn; sred[4 + (tid >> 6)] = lmx; }
    __syncthreads();
    const float mn = fminf(sred[0], sred[1]);
    const float mx = fmaxf(sred[4], sred[5]);
    const float inv = __builtin_amdgcn_rcpf(mx - mn + 1e-8f);

    int pos = t & 32767;
    int i  = pos >> 6;
    int j0 = (pos & 63) << 3;
    const size_t ibase = (size_t)img << 18;

    int ri = (i - 1) & 511;
    const float* rrow = rho + ibase + ((size_t)ri << 9);
    float4 ra = *(const float4*)(rrow + j0);
    float4 rb = *(const float4*)(rrow + j0 + 4);
    float rm1 = rrow[(j0 - 1) & 511];
    float r[8] = {rm1, ra.x, ra.y, ra.z, ra.w, rb.x, rb.y, rb.z};

    const float* xrow = x + ibase + ((size_t)i << 9) + j0;
    float4 xa = *(const float4*)xrow;
    float4 xb = *(const float4*)(xrow + 4);
    float xs[8] = {xa.x, xa.y, xa.z, xa.w, xb.x, xb.y, xb.z, xb.w};
    float os[8];
    #pragma unroll
    for (int k = 0; k < 8; ++k) {
        float rn = (r[k] - mn) * inv;
        os[k] = xs[k] * __builtin_amdgcn_rcpf(1.f + __expf(rn - 1.f));  // x * sigmoid(1-rn)
    }
    float* orow = out + ibase + ((size_t)i << 9) + j0;
    *(float4*)orow       = make_float4(os[0], os[1], os[2], os[3]);
    *(float4*)(orow + 4) = make_float4(os[4], os[5], os[6], os[7]);
}

extern "C" void kernel_launch(void* const* d_in, const int* in_sizes, int n_in,
                              void* d_out, int out_size, void* d_ws, size_t ws_size,
                              hipStream_t stream) {
    const float* x    = (const float*)d_in[0];
    const float* hpdf = (const float*)d_in[1];
    float* out = (float*)d_out;

    float* rho  = (float*)d_ws;                                          // 24*512*512 fp32
    float2* bmm = (float2*)((char*)d_ws + (size_t)NIMG * IMG * IMG * 4); // 24*128 float2

    hipLaunchKernelGGL(stego_stage1, dim3(IMG / 32, IMG / 64, NIMG), dim3(512), 0, stream,
                       x, hpdf, rho, bmm);
    const int total8 = NIMG * IMG * IMG / 8;
    hipLaunchKernelGGL(stego_stage2, dim3(total8 / 256), dim3(256), 0, stream,
                       x, rho, bmm, out);
}

// Round 9
// 139.817 us; speedup vs baseline: 1.9194x; 1.0152x over previous
//
#include <hip/hip_runtime.h>
#include <math.h>

#define IMG   512
#define NIMG  24
#define SXH   72     // X fp16 stride (halfs) = 36 dw
#define STH   104    // T' stride
#define SRH   56     // R  stride
#define SUH   88     // U' stride
#define XROWS 94
#define UOFF  4480
#define P1SZ  7296
#define TSZ   (48 * STH)

typedef _Float16 half2t __attribute__((ext_vector_type(2)));

__device__ __forceinline__ half2t bch2(unsigned u) {
    union { unsigned u; half2t h; } c; c.u = u; return c.h;
}

__device__ __forceinline__ unsigned pkrtz(float a, float b) {
    union { __fp16 __attribute__((ext_vector_type(2))) v; unsigned u; } c;
    c.v = __builtin_amdgcn_cvt_pkrtz(a, b);
    return c.u;
}

// float -> bf16 bits, round-to-nearest-even (input guaranteed non-NaN)
__device__ __forceinline__ unsigned short f2bf(float f) {
    unsigned b = __float_as_uint(f);
    b = (b + 0x7fffu + ((b >> 16) & 1u)) >> 16;
    return (unsigned short)b;
}

// coefficient modes (h = hpdf, lpdf[v] = (-1)^v h[15-v]):
// 0: h[v]   1: lpdf[v]   2: |h[v]|   3: |h[15-v]|
template<int MODE>
__device__ __forceinline__ float coef(const float* __restrict__ h, int v) {
    if (MODE == 0) return h[v];
    if (MODE == 1) return (v & 1) ? -h[15 - v] : h[15 - v];
    if (MODE == 2) return fabsf(h[v]);
    return fabsf(h[15 - v]);
}

template<int MODE>
__device__ __forceinline__ void build_cp(const float* __restrict__ h, half2t cp[8]) {
    #pragma unroll
    for (int k = 0; k < 8; ++k) {
        half2t p;
        p.x = (_Float16)coef<MODE>(h, 2 * k);
        p.y = (_Float16)coef<MODE>(h, 2 * k + 1);
        cp[k] = p;
    }
}

__device__ __forceinline__ int refl(int g) {
    return g < 0 ? -g : (g >= IMG ? 2 * IMG - 2 - g : g);
}

// 8-output 16-tap conv via dot2; window = halfs [0,23) at 16B-aligned LDS base.
template<int MODE>
__device__ __forceinline__ void conv8(const _Float16* __restrict__ base,
                                      const float* __restrict__ h, float out[8]) {
    const uint4* b4 = (const uint4*)base;
    uint4 A0 = b4[0], A1 = b4[1], A2 = b4[2];
    unsigned up[12] = {A0.x, A0.y, A0.z, A0.w, A1.x, A1.y, A1.z, A1.w, A2.x, A2.y, A2.z, A2.w};
    half2t cp[8]; build_cp<MODE>(h, cp);
    #pragma unroll
    for (int m = 0; m < 4; ++m) {
        float acc = 0.f;
        #pragma unroll
        for (int k = 0; k < 8; ++k) acc = __builtin_amdgcn_fdot2(cp[k], bch2(up[m + k]), acc, false);
        out[2 * m] = acc;
    }
    unsigned uq[11];
    #pragma unroll
    for (int k = 0; k < 11; ++k) uq[k] = (up[k] >> 16) | (up[k + 1] << 16);
    #pragma unroll
    for (int m = 0; m < 4; ++m) {
        float acc = 0.f;
        #pragma unroll
        for (int k = 0; k < 8; ++k) acc = __builtin_amdgcn_fdot2(cp[k], bch2(uq[m + k]), acc, false);
        out[2 * m + 1] = acc;
    }
}

// fused two-filter variant for stage A (one window read, two coef sets)
__device__ __forceinline__ void conv8x2(const _Float16* __restrict__ base,
                                        const float* __restrict__ h,
                                        float oL[8], float oH[8]) {
    const uint4* b4 = (const uint4*)base;
    uint4 A0 = b4[0], A1 = b4[1], A2 = b4[2];
    unsigned up[12] = {A0.x, A0.y, A0.z, A0.w, A1.x, A1.y, A1.z, A1.w, A2.x, A2.y, A2.z, A2.w};
    half2t cL[8], cH[8];
    build_cp<1>(h, cL); build_cp<0>(h, cH);
    #pragma unroll
    for (int m = 0; m < 4; ++m) {
        float aL = 0.f, aH = 0.f;
        #pragma unroll
        for (int k = 0; k < 8; ++k) {
            half2t w = bch2(up[m + k]);
            aL = __builtin_amdgcn_fdot2(cL[k], w, aL, false);
            aH = __builtin_amdgcn_fdot2(cH[k], w, aH, false);
        }
        oL[2 * m] = aL; oH[2 * m] = aH;
    }
    unsigned uq[11];
    #pragma unroll
    for (int k = 0; k < 11; ++k) uq[k] = (up[k] >> 16) | (up[k + 1] << 16);
    #pragma unroll
    for (int m = 0; m < 4; ++m) {
        float aL = 0.f, aH = 0.f;
        #pragma unroll
        for (int k = 0; k < 8; ++k) {
            half2t w = bch2(uq[m + k]);
            aL = __builtin_amdgcn_fdot2(cL[k], w, aL, false);
            aH = __builtin_amdgcn_fdot2(cH[k], w, aH, false);
        }
        oL[2 * m + 1] = aL; oH[2 * m + 1] = aH;
    }
}

// 4-output conv for stage D; window halfs [0,20) at 8B-aligned base.
template<int MODE>
__device__ __forceinline__ void conv4(const _Float16* __restrict__ base,
                                      const float* __restrict__ h, float out[4]) {
    const uint2* b2 = (const uint2*)base;
    unsigned up[10];
    #pragma unroll
    for (int k = 0; k < 5; ++k) { uint2 t = b2[k]; up[2 * k] = t.x; up[2 * k + 1] = t.y; }
    half2t cp[8]; build_cp<MODE>(h, cp);
    #pragma unroll
    for (int m = 0; m < 2; ++m) {
        float acc = 0.f;
        #pragma unroll
        for (int k = 0; k < 8; ++k) acc = __builtin_amdgcn_fdot2(cp[k], bch2(up[m + k]), acc, false);
        out[2 * m] = acc;
    }
    unsigned uq[9];
    #pragma unroll
    for (int k = 0; k < 9; ++k) uq[k] = (up[k] >> 16) | (up[k + 1] << 16);
    #pragma unroll
    for (int m = 0; m < 2; ++m) {
        float acc = 0.f;
        #pragma unroll
        for (int k = 0; k < 8; ++k) acc = __builtin_amdgcn_fdot2(cp[k], bch2(uq[m + k]), acc, false);
        out[2 * m + 1] = acc;
    }
}

// B: vconv over T' rows; writes R fp16. 480 units.
template<int MODE>
__device__ __forceinline__ void stageB(const _Float16* __restrict__ pt, _Float16* __restrict__ pr,
                                       const float* __restrict__ h, int tid) {
    if (tid < 480) {
        int s = tid / 48, jr = tid - s * 48;
        float o[8]; conv8<MODE>(pt + jr * STH + s * 8, h, o);
        #pragma unroll
        for (int k = 0; k < 8; ++k) pr[(s * 8 + k) * SRH + jr] = (_Float16)fabsf(o[k]);
    }
}

// C: hconv over R rows; writes U' transposed fp16. 316 units.
template<int MODE>
__device__ __forceinline__ void stageC(const _Float16* __restrict__ pr, _Float16* __restrict__ pu,
                                       const float* __restrict__ h, int tid) {
    if (tid < 316) {
        int s = tid / 79, i = tid - s * 79;
        float o[8]; conv8<MODE>(pr + i * SRH + s * 8, h, o);
        #pragma unroll
        for (int k = 0; k < 8; ++k) pu[(s * 8 + k) * SUH + i] = (_Float16)o[k];
    }
}

// D: vconv over U' rows (LEN=4); rho += 1/xi. All 512 threads.
template<int MODE>
__device__ __forceinline__ void stageD(const _Float16* __restrict__ pu, const float* __restrict__ h,
                                       int tid, float rho[4]) {
    int col = tid & 31, sg = tid >> 5;
    float o[4]; conv4<MODE>(pu + col * SUH + sg * 4, h, o);
    #pragma unroll
    for (int k = 0; k < 4; ++k) rho[k] += __builtin_amdgcn_rcpf(o[k]);
}

// ---------------- stage 1: rho (bf16, pre-rolled) + per-block min/max ----------------
__global__ __launch_bounds__(512, 8) void stego_stage1(
    const float* __restrict__ x, const float* __restrict__ hpdf,
    unsigned short* __restrict__ rho_out, float2* __restrict__ bmm)
{
    __shared__ __align__(16) _Float16 pool1[P1SZ];   // X (94x72), then R (80x56) + U' (32x88)
    __shared__ __align__(16) _Float16 sTL[TSZ];      // T_L'
    __shared__ __align__(16) _Float16 sTH[TSZ];      // T_H' (kept across LH and HH)
    __shared__ float red[16];

    const int tid = threadIdx.x;
    const int Oj = blockIdx.x * 32;
    const int Oi = blockIdx.y * 64;
    const int img = blockIdx.z;
    const float* ximg = x + (size_t)img * IMG * IMG;

    // ---- load X as fp16: 94 rows x 64 cols ----
    {
        const int cp2 = tid & 31, row0 = tid >> 5;
        const int c0 = Oj - 15 + 2 * cp2;
        if (Oi >= 15 && Oi <= 433 && Oj >= 15 && Oj <= 463) {
            const float* src = ximg + (size_t)(Oi - 15) * IMG + c0;
            #pragma unroll
            for (int k = 0; k < 6; ++k) {
                int i = row0 + (k << 4);
                if (i < XROWS) {
                    float v0 = src[(size_t)i * IMG], v1 = src[(size_t)i * IMG + 1];
                    *(unsigned*)(pool1 + i * SXH + 2 * cp2) = pkrtz(v0, v1);
                }
            }
        } else {
            int gj0 = refl(c0), gj1 = refl(c0 + 1);
            #pragma unroll
            for (int k = 0; k < 6; ++k) {
                int i = row0 + (k << 4);
                if (i < XROWS) {
                    int gi = refl(Oi - 15 + i);
                    float v0 = ximg[gi * IMG + gj0], v1 = ximg[gi * IMG + gj1];
                    *(unsigned*)(pool1 + i * SXH + 2 * cp2) = pkrtz(v0, v1);
                }
            }
        }
    }
    __syncthreads();

    // ---- A (fused L+H): 564 units ----
    #pragma unroll
    for (int uu = 0; uu < 2; ++uu) {
        int u = tid + uu * 512;
        if (u < 564) {
            int s = u / 94, r = u - s * 94;
            float oL[8], oH[8];
            conv8x2(pool1 + r * SXH + s * 8, hpdf, oL, oH);
            #pragma unroll
            for (int o = 0; o < 8; ++o) {
                sTL[(s * 8 + o) * STH + r] = (_Float16)oL[o];
                sTH[(s * 8 + o) * STH + r] = (_Float16)oH[o];
            }
        }
    }
    __syncthreads();

    float rho[4] = {0.f, 0.f, 0.f, 0.f};
    _Float16* Rb = pool1;
    _Float16* Ub = pool1 + UOFF;

    // ---- HL ----
    stageB<0>(sTL, Rb, hpdf, tid);  __syncthreads();
    stageC<2>(Rb, Ub, hpdf, tid);   __syncthreads();
    // ---- LH (D of HL overlaps B of LH) ----
    stageD<3>(Ub, hpdf, tid, rho);
    stageB<1>(sTH, Rb, hpdf, tid);  __syncthreads();
    stageC<3>(Rb, Ub, hpdf, tid);   __syncthreads();
    // ---- HH ----
    stageD<2>(Ub, hpdf, tid, rho);
    stageB<0>(sTH, Rb, hpdf, tid);  __syncthreads();
    stageC<3>(Rb, Ub, hpdf, tid);   __syncthreads();
    stageD<3>(Ub, hpdf, tid, rho);

    // ---- finalize: clamp/NaN, bf16-round, store PRE-ROLLED, min/max on rounded values ----
    const int col = tid & 31, sg = tid >> 5, wid = tid >> 6;
    float lmin = 1e38f, lmax = 0.f;
    const size_t rbase = (size_t)img * (IMG * IMG);
    const int j_out = (Oj + col + 1) & 511;
    #pragma unroll
    for (int t = 0; t < 4; ++t) {
        float r = rho[t];
        r = isnan(r) ? 1e10f : fminf(r, 1e10f);
        unsigned short b = f2bf(r);
        int i_out = (Oi + sg * 4 + t + 1) & 511;
        rho_out[rbase + ((size_t)i_out << 9) + j_out] = b;
        float rq = __uint_as_float((unsigned)b << 16);
        lmin = fminf(lmin, rq);
        lmax = fmaxf(lmax, rq);
    }
    #pragma unroll
    for (int off = 32; off >= 1; off >>= 1) {
        lmin = fminf(lmin, __shfl_xor(lmin, off));
        lmax = fmaxf(lmax, __shfl_xor(lmax, off));
    }
    if ((tid & 63) == 0) { red[wid] = lmin; red[8 + wid] = lmax; }
    __syncthreads();
    if (tid == 0) {
        float m0 = red[0], m1 = red[8];
        #pragma unroll
        for (int k = 1; k < 8; ++k) { m0 = fminf(m0, red[k]); m1 = fmaxf(m1, red[8 + k]); }
        bmm[(img << 7) + blockIdx.y * 16 + blockIdx.x] = make_float2(m0, m1);
    }
}

// ---------------- stage 2: reduce minmax + normalize + sigmoid + multiply (8 px/thr) ----------------
__global__ __launch_bounds__(256) void stego_stage2(
    const float* __restrict__ x, const unsigned short* __restrict__ rho,
    const float2* __restrict__ bmm, float* __restrict__ out)
{
    __shared__ float sred[8];
    const int tid = threadIdx.x;
    const int t = blockIdx.x * 256 + tid;      // group of 8 elements
    const int img = t >> 15;                   // 32768 groups per image

    // prologue: reduce this image's 128 per-block (min,max) pairs
    float lmn = 1e38f, lmx = 0.f;
    if (tid < 128) { float2 p = bmm[(img << 7) + tid]; lmn = p.x; lmx = p.y; }
    #pragma unroll
    for (int off = 32; off >= 1; off >>= 1) {
        lmn = fminf(lmn, __shfl_xor(lmn, off));
        lmx = fmaxf(lmx, __shfl_xor(lmx, off));
    }
    if (tid < 128 && (tid & 63) == 0) { sred[tid >> 6] = lmn; sred[4 + (tid >> 6)] = lmx; }
    __syncthreads();
    const float mn = fminf(sred[0], sred[1]);
    const float mx = fmaxf(sred[4], sred[5]);
    const float inv = __builtin_amdgcn_rcpf(mx - mn + 1e-8f);

    const size_t base = (size_t)t << 3;        // flat element index (pre-rolled rho: fully aligned)
    uint4 rb = *(const uint4*)(rho + base);    // 8 bf16
    unsigned ru[4] = {rb.x, rb.y, rb.z, rb.w};
    float r[8];
    #pragma unroll
    for (int k = 0; k < 4; ++k) {
        r[2 * k]     = __uint_as_float(ru[k] << 16);
        r[2 * k + 1] = __uint_as_float(ru[k] & 0xffff0000u);
    }

    const float* xrow = x + base;
    float4 xa = *(const float4*)xrow;
    float4 xb = *(const float4*)(xrow + 4);
    float xs[8] = {xa.x, xa.y, xa.z, xa.w, xb.x, xb.y, xb.z, xb.w};
    float os[8];
    #pragma unroll
    for (int k = 0; k < 8; ++k) {
        float rn = (r[k] - mn) * inv;
        os[k] = xs[k] * __builtin_amdgcn_rcpf(1.f + __expf(rn - 1.f));  // x * sigmoid(1-rn)
    }
    float* orow = out + base;
    *(float4*)orow       = make_float4(os[0], os[1], os[2], os[3]);
    *(float4*)(orow + 4) = make_float4(os[4], os[5], os[6], os[7]);
}

extern "C" void kernel_launch(void* const* d_in, const int* in_sizes, int n_in,
                              void* d_out, int out_size, void* d_ws, size_t ws_size,
                              hipStream_t stream) {
    const float* x    = (const float*)d_in[0];
    const float* hpdf = (const float*)d_in[1];
    float* out = (float*)d_out;

    unsigned short* rho = (unsigned short*)d_ws;                         // 24*512*512 bf16
    float2* bmm = (float2*)((char*)d_ws + (size_t)NIMG * IMG * IMG * 2); // 24*128 float2

    hipLaunchKernelGGL(stego_stage1, dim3(IMG / 32, IMG / 64, NIMG), dim3(512), 0, stream,
                       x, hpdf, rho, bmm);
    const int total8 = NIMG * IMG * IMG / 8;
    hipLaunchKernelGGL(stego_stage2, dim3(total8 / 256), dim3(256), 0, stream,
                       x, rho, bmm, out);
}

// Round 10
// 118.690 us; speedup vs baseline: 2.2611x; 1.1780x over previous
//
#include <hip/hip_runtime.h>
#include <math.h>

#define IMG   512
#define NIMG  24
#define XST   72     // X stride (halfs): 36 dw == 4 mod 8, rows 16B-aligned
#define TST   104    // T' stride (row length 96)
#define RST   56     // R stride (row length 48)
#define UST   88     // U' stride (row length 80)
#define UOFF  4480   // U' offset in pool1 (R = 80*56 = 4480)
#define P1SZ  7296   // max(X 96*72=6912, R+U' 4480+2816=7296)
#define TSZ   (48 * TST)

typedef _Float16 v8h __attribute__((ext_vector_type(8)));
typedef float    v4f __attribute__((ext_vector_type(4)));

__device__ __forceinline__ v8h load8(const _Float16* p) {
    union { uint4 u; v8h h; } c;
    c.u = *(const uint4*)p;
    return c.h;
}

__device__ __forceinline__ void store4(_Float16* p, v4f a) {
    union { _Float16 h[4]; uint2 u; } c;
    c.h[0] = (_Float16)a[0]; c.h[1] = (_Float16)a[1];
    c.h[2] = (_Float16)a[2]; c.h[3] = (_Float16)a[3];
    *(uint2*)p = c.u;
}

__device__ __forceinline__ void store4abs(_Float16* p, v4f a) {
    union { _Float16 h[4]; uint2 u; } c;
    c.h[0] = (_Float16)fabsf(a[0]); c.h[1] = (_Float16)fabsf(a[1]);
    c.h[2] = (_Float16)fabsf(a[2]); c.h[3] = (_Float16)fabsf(a[3]);
    *(uint2*)p = c.u;
}

__device__ __forceinline__ unsigned pkrtz(float a, float b) {
    union { __fp16 __attribute__((ext_vector_type(2))) v; unsigned u; } c;
    c.v = __builtin_amdgcn_cvt_pkrtz(a, b);
    return c.u;
}

// float -> bf16 bits, round-to-nearest-even (input non-NaN)
__device__ __forceinline__ unsigned short f2bf(float f) {
    unsigned b = __float_as_uint(f);
    b = (b + 0x7fffu + ((b >> 16) & 1u)) >> 16;
    return (unsigned short)b;
}

__device__ __forceinline__ int refl(int g) {
    return g < 0 ? -g : (g >= IMG ? 2 * IMG - 2 - g : g);
}

// ---------------- stage 1: MFMA banded-conv pipeline ----------------
// modes: 0: h[v]  1: lpdf[v]=(-1)^v h[15-v]  2: |h[v]|  3: |h[15-v]|
__global__ __launch_bounds__(512, 6) void stego_stage1(
    const float* __restrict__ x, const float* __restrict__ hpdf,
    unsigned short* __restrict__ rho_out, float2* __restrict__ bmm)
{
    __shared__ __align__(16) _Float16 pool1[P1SZ];   // X (96x72), then R (80x56) + U' (32x88)
    __shared__ __align__(16) _Float16 sTL[TSZ];      // T_L' [col j][row i], 48 x 104
    __shared__ __align__(16) _Float16 sTH[TSZ];      // T_H'
    __shared__ __align__(16) _Float16 btab[256];     // band coef table, 4 modes x 64
    __shared__ float red[16];

    const int tid = threadIdx.x;
    const int lane = tid & 63, wid = tid >> 6;
    const int n16 = lane & 15, quad = lane >> 4;
    const int Oj = blockIdx.x * 32, Oi = blockIdx.y * 64, img = blockIdx.z;
    const float* ximg = x + (size_t)img * IMG * IMG;

    // band coefficient table: btab[mode*64 + 16 + t] = c_mode[t] (t in 0..15), zeros elsewhere
    if (tid < 256) {
        int mode = tid >> 6, t = tid & 63;
        float v = 0.f;
        if (t >= 16 && t < 32) {
            int tap = t - 16;
            int idx = (mode == 0 || mode == 2) ? tap : 15 - tap;
            float c = hpdf[idx];
            if (mode == 1 && (tap & 1)) c = -c;
            if (mode >= 2) c = fabsf(c);
            v = c;
        }
        btab[tid] = (_Float16)v;
    }

    // ---- load X as fp16: rows 0..93 data (reflect-padded), rows 94..95 zero ----
    {
        const int cp2 = tid & 31, row0 = tid >> 5;   // 32 col-pairs x 16 rows, 6 steps = 96 rows
        const int c0 = Oj - 15 + 2 * cp2;
        if (Oi >= 15 && Oi <= 433 && Oj >= 15 && Oj <= 463) {
            const float* src = ximg + (size_t)(Oi - 15) * IMG + c0;
            #pragma unroll
            for (int k = 0; k < 6; ++k) {
                int i = row0 + (k << 4);
                unsigned pv = 0;
                if (i < 94) pv = pkrtz(src[(size_t)i * IMG], src[(size_t)i * IMG + 1]);
                *(unsigned*)(pool1 + i * XST + 2 * cp2) = pv;
            }
        } else {
            int gj0 = refl(c0), gj1 = refl(c0 + 1);
            #pragma unroll
            for (int k = 0; k < 6; ++k) {
                int i = row0 + (k << 4);
                unsigned pv = 0;
                if (i < 94) {
                    int gi = refl(Oi - 15 + i);
                    pv = pkrtz(ximg[gi * IMG + gj0], ximg[gi * IMG + gj1]);
                }
                *(unsigned*)(pool1 + i * XST + 2 * cp2) = pv;
            }
        }
    }
    __syncthreads();

    // ---- build 4 band B-fragments: B[k][n] = c[k-n]; lane n=lane&15, k=quad*8+j ----
    v8h band[4];
    {
        const int boff = 16 + quad * 8 - n16;   // + j in [1,47]
        #pragma unroll
        for (int m = 0; m < 4; ++m)
            #pragma unroll
            for (int j = 0; j < 8; ++j)
                band[m][j] = btab[m * 64 + boff + j];
    }

    // ---- stage A: hconv X -> T_L', T_H' (18 tiles, shared A-frag, 2 MFMA each) ----
    // D[m][n] = sum_k X[m0+m][n0+k] c[k-n] = T[m0+m][n0+n]; store transposed.
    for (int u = wid; u < 18; u += 8) {
        int mt = u % 6, nt = u / 6;
        int m0 = mt * 16, n0 = nt * 16;
        v8h a = load8(pool1 + (m0 + n16) * XST + n0 + quad * 8);
        v4f z = {0.f, 0.f, 0.f, 0.f};
        v4f cL = __builtin_amdgcn_mfma_f32_16x16x32_f16(a, band[1], z, 0, 0, 0);
        v4f cH = __builtin_amdgcn_mfma_f32_16x16x32_f16(a, band[0], z, 0, 0, 0);
        int off = (n0 + n16) * TST + m0 + quad * 4;   // T'[col][row..row+3]
        store4(sTL + off, cL);
        store4(sTH + off, cH);
    }
    __syncthreads();

    float rho[4] = {0.f, 0.f, 0.f, 0.f};
    _Float16* Rb = pool1;
    _Float16* Ub = pool1 + UOFF;

    const int fB[3] = {0, 1, 0};   // HL: a=H, LH: a=L, HH: a=H
    const int fC[3] = {2, 3, 3};   // b2 mode
    const int fD[3] = {3, 2, 3};   // a2 mode

    #pragma unroll
    for (int f = 0; f < 3; ++f) {
        const _Float16* Tsrc = (f == 0) ? sTL : sTH;

        // B: vconv T -> R = |.| (15 tiles). A[m][k]=T'[c0+m][i0+k], D[m][n]=R[i0+n][c0+m]
        for (int u = wid; u < 15; u += 8) {
            int nt = u % 5, mt = u / 5;
            int i0 = nt * 16, c0 = mt * 16;
            v8h a = load8(Tsrc + (c0 + n16) * TST + i0 + quad * 8);
            v4f z = {0.f, 0.f, 0.f, 0.f};
            v4f acc = __builtin_amdgcn_mfma_f32_16x16x32_f16(a, band[fB[f]], z, 0, 0, 0);
            store4abs(Rb + (i0 + n16) * RST + c0 + quad * 4, acc);   // R natural [i][j..j+3]
        }
        __syncthreads();

        // C: hconv R -> U' (10 tiles). A[m][k]=R[i0+m][j0+k], D[m][n]=U[i0+m][j0+n]
        for (int u = wid; u < 10; u += 8) {
            int mt = u % 5, nt = u / 5;
            int i0 = mt * 16, j0 = nt * 16;
            v8h a = load8(Rb + (i0 + n16) * RST + j0 + quad * 8);
            v4f z = {0.f, 0.f, 0.f, 0.f};
            v4f acc = __builtin_amdgcn_mfma_f32_16x16x32_f16(a, band[fC[f]], z, 0, 0, 0);
            store4(Ub + (j0 + n16) * UST + i0 + quad * 4, acc);      // U'[col][row..row+3]
        }
        __syncthreads();

        // D: vconv U -> xi; rho += 1/xi (8 tiles, 1/wave). D[m][n]=xi[i0+n][c0+m]
        {
            int i0 = (wid & 3) * 16, c0 = (wid >> 2) * 16;
            v8h a = load8(Ub + (c0 + n16) * UST + i0 + quad * 8);
            v4f z = {0.f, 0.f, 0.f, 0.f};
            v4f acc = __builtin_amdgcn_mfma_f32_16x16x32_f16(a, band[fD[f]], z, 0, 0, 0);
            #pragma unroll
            for (int r = 0; r < 4; ++r) rho[r] += __builtin_amdgcn_rcpf(acc[r]);
        }
        // no barrier: next B writes R (disjoint from U'); U' overwritten only after next barrier
    }

    // ---- finalize: clamp/NaN, bf16 round, store PRE-ROLLED, per-block min/max ----
    const size_t rbase = (size_t)img * (IMG * IMG);
    const int i_out = (Oi + (wid & 3) * 16 + n16 + 1) & 511;
    const int c0f = (wid >> 2) * 16;
    float lmin = 1e38f, lmax = 0.f;
    #pragma unroll
    for (int r = 0; r < 4; ++r) {
        float v = rho[r];
        v = isnan(v) ? 1e10f : fminf(v, 1e10f);
        unsigned short b = f2bf(v);
        int j_out = (Oj + c0f + quad * 4 + r + 1) & 511;
        rho_out[rbase + ((size_t)i_out << 9) + j_out] = b;
        float rq = __uint_as_float((unsigned)b << 16);
        lmin = fminf(lmin, rq);
        lmax = fmaxf(lmax, rq);
    }
    #pragma unroll
    for (int off = 32; off >= 1; off >>= 1) {
        lmin = fminf(lmin, __shfl_xor(lmin, off));
        lmax = fmaxf(lmax, __shfl_xor(lmax, off));
    }
    if ((tid & 63) == 0) { red[wid] = lmin; red[8 + wid] = lmax; }
    __syncthreads();
    if (tid == 0) {
        float m0 = red[0], m1 = red[8];
        #pragma unroll
        for (int k = 1; k < 8; ++k) { m0 = fminf(m0, red[k]); m1 = fmaxf(m1, red[8 + k]); }
        bmm[(img << 7) + blockIdx.y * 16 + blockIdx.x] = make_float2(m0, m1);
    }
}

// ---------------- stage 2: reduce minmax + normalize + sigmoid + multiply (8 px/thr) ----------------
__global__ __launch_bounds__(256) void stego_stage2(
    const float* __restrict__ x, const unsigned short* __restrict__ rho,
    const float2* __restrict__ bmm, float* __restrict__ out)
{
    __shared__ float sred[8];
    const int tid = threadIdx.x;
    const int t = blockIdx.x * 256 + tid;      // group of 8 elements
    const int img = t >> 15;                   // 32768 groups per image

    float lmn = 1e38f, lmx = 0.f;
    if (tid < 128) { float2 p = bmm[(img << 7) + tid]; lmn = p.x; lmx = p.y; }
    #pragma unroll
    for (int off = 32; off >= 1; off >>= 1) {
        lmn = fminf(lmn, __shfl_xor(lmn, off));
        lmx = fmaxf(lmx, __shfl_xor(lmx, off));
    }
    if (tid < 128 && (tid & 63) == 0) { sred[tid >> 6] = lmn; sred[4 + (tid >> 6)] = lmx; }
    __syncthreads();
    const float mn = fminf(sred[0], sred[1]);
    const float mx = fmaxf(sred[4], sred[5]);
    const float inv = __builtin_amdgcn_rcpf(mx - mn + 1e-8f);

    const size_t base = (size_t)t << 3;
    uint4 rb = *(const uint4*)(rho + base);    // 8 bf16 (pre-rolled, aligned)
    unsigned ru[4] = {rb.x, rb.y, rb.z, rb.w};
    float r[8];
    #pragma unroll
    for (int k = 0; k < 4; ++k) {
        r[2 * k]     = __uint_as_float(ru[k] << 16);
        r[2 * k + 1] = __uint_as_float(ru[k] & 0xffff0000u);
    }

    const float* xrow = x + base;
    float4 xa = *(const float4*)xrow;
    float4 xb = *(const float4*)(xrow + 4);
    float xs[8] = {xa.x, xa.y, xa.z, xa.w, xb.x, xb.y, xb.z, xb.w};
    float os[8];
    #pragma unroll
    for (int k = 0; k < 8; ++k) {
        float rn = (r[k] - mn) * inv;
        os[k] = xs[k] * __builtin_amdgcn_rcpf(1.f + __expf(rn - 1.f));  // x * sigmoid(1-rn)
    }
    float* orow = out + base;
    *(float4*)orow       = make_float4(os[0], os[1], os[2], os[3]);
    *(float4*)(orow + 4) = make_float4(os[4], os[5], os[6], os[7]);
}

extern "C" void kernel_launch(void* const* d_in, const int* in_sizes, int n_in,
                              void* d_out, int out_size, void* d_ws, size_t ws_size,
                              hipStream_t stream) {
    const float* x    = (const float*)d_in[0];
    const float* hpdf = (const float*)d_in[1];
    float* out = (float*)d_out;

    unsigned short* rho = (unsigned short*)d_ws;                         // 24*512*512 bf16
    float2* bmm = (float2*)((char*)d_ws + (size_t)NIMG * IMG * IMG * 2); // 24*128 float2

    hipLaunchKernelGGL(stego_stage1, dim3(IMG / 32, IMG / 64, NIMG), dim3(512), 0, stream,
                       x, hpdf, rho, bmm);
    const int total8 = NIMG * IMG * IMG / 8;
    hipLaunchKernelGGL(stego_stage2, dim3(total8 / 256), dim3(256), 0, stream,
                       x, rho, bmm, out);
}